// Round 1
// baseline (4974.992 us; speedup 1.0000x reference)
//
#include <hip/hip_runtime.h>
#include <math.h>

#define N_NODES 10000
#define FEAT 512
#define HID 256
#define EMB 128
#define NC 10
#define NE_EDGES 160000
#define KTOP 10
#define NNB 9

// ---- phase-1 / phase-2 kNN parameters ----
#define P1_ROWS 128
#define P1_COLS 128
#define P1_KC 32
#define NSPLIT 8
#define CPS 16                         // candidates kept per split
#define NCAND (NSPLIT * CPS)           // 128
#define SPLITW ((N_NODES + NSPLIT - 1) / NSPLIT)  // 1250

// -------------------- row norms --------------------
__global__ void k_norms(const float* __restrict__ x, float* __restrict__ xn,
                        double* __restrict__ rinv) {
  const int row = blockIdx.x;
  const int t = threadIdx.x;  // 128
  const float* xr = x + (size_t)row * FEAT;
  double s = 0.0;
  for (int k = t; k < FEAT; k += 128) { const double v = (double)xr[k]; s += v * v; }
  __shared__ double red[128];
  red[t] = s;
  __syncthreads();
  for (int o = 64; o > 0; o >>= 1) {
    if (t < o) red[t] += red[t + o];
    __syncthreads();
  }
  const double inv = 1.0 / fmax(sqrt(red[0]), 1e-12);
  const float finv = (float)inv;
  for (int k = t; k < FEAT; k += 128) xn[(size_t)row * FEAT + k] = xr[k] * finv;
  if (t == 0) rinv[row] = inv;
}

// -------------------- phase 1: f32 sim + top-16 candidates per column split --------------------
__global__ __launch_bounds__(256, 2) void k_phase1(const float* __restrict__ xn,
                                                   int* __restrict__ cand) {
  __shared__ float As[P1_KC][132];
  __shared__ float Bs[P1_KC][132];
  __shared__ float simbuf[16][128];
  __shared__ float tval[128][CPS];
  __shared__ int tidx[128][CPS];

  const int t = threadIdx.x;
  const int ty = t >> 4, tx = t & 15;
  const int r0 = blockIdx.x * P1_ROWS;
  const int cstart = blockIdx.y * SPLITW;
  const int cend = min(cstart + SPLITW, N_NODES);

  int cnt = 0, minpos = 0;
  float minval = -3e38f;

  const int nct = (cend - cstart + P1_COLS - 1) / P1_COLS;
  for (int cb = 0; cb < nct; ++cb) {
    const int c0 = cstart + cb * P1_COLS;
    float acc[8][8];
#pragma unroll
    for (int i = 0; i < 8; ++i)
#pragma unroll
      for (int j = 0; j < 8; ++j) acc[i][j] = 0.f;

    for (int kc = 0; kc < FEAT; kc += P1_KC) {
      {
        const int r = t >> 1;
        const int kb = (t & 1) * 16;
        const int gr = min(r0 + r, N_NODES - 1);
        const float* pa = xn + (size_t)gr * FEAT + kc + kb;
#pragma unroll
        for (int q = 0; q < 4; ++q) {
          const float4 v = *(const float4*)(pa + 4 * q);
          As[kb + 4 * q + 0][r] = v.x;
          As[kb + 4 * q + 1][r] = v.y;
          As[kb + 4 * q + 2][r] = v.z;
          As[kb + 4 * q + 3][r] = v.w;
        }
        const int gc = min(c0 + r, N_NODES - 1);
        const float* pb = xn + (size_t)gc * FEAT + kc + kb;
#pragma unroll
        for (int q = 0; q < 4; ++q) {
          const float4 v = *(const float4*)(pb + 4 * q);
          Bs[kb + 4 * q + 0][r] = v.x;
          Bs[kb + 4 * q + 1][r] = v.y;
          Bs[kb + 4 * q + 2][r] = v.z;
          Bs[kb + 4 * q + 3][r] = v.w;
        }
      }
      __syncthreads();
#pragma unroll
      for (int k = 0; k < P1_KC; ++k) {
        const float4 a0 = *(const float4*)&As[k][ty * 8];
        const float4 a1 = *(const float4*)&As[k][ty * 8 + 4];
        const float4 b0 = *(const float4*)&Bs[k][tx * 8];
        const float4 b1 = *(const float4*)&Bs[k][tx * 8 + 4];
        const float av[8] = {a0.x, a0.y, a0.z, a0.w, a1.x, a1.y, a1.z, a1.w};
        const float bv[8] = {b0.x, b0.y, b0.z, b0.w, b1.x, b1.y, b1.z, b1.w};
#pragma unroll
        for (int i = 0; i < 8; ++i)
#pragma unroll
          for (int j = 0; j < 8; ++j) acc[i][j] += av[i] * bv[j];
      }
      __syncthreads();
    }

    const int cmax = min(P1_COLS, cend - c0);
#pragma unroll
    for (int p = 0; p < 8; ++p) {
#pragma unroll
      for (int j = 0; j < 8; ++j) simbuf[ty][tx * 8 + j] = acc[p][j];
      __syncthreads();
      if (t < 128 && (t & 7) == p && (r0 + t) < N_NODES) {
        const int sub = t >> 3;
        for (int c = 0; c < cmax; ++c) {
          const float v = simbuf[sub][c];
          if (cnt < CPS) {
            tval[t][cnt] = v;
            tidx[t][cnt] = c0 + c;
            ++cnt;
            if (cnt == CPS) {
              float mv = tval[t][0];
              int mp = 0;
#pragma unroll
              for (int q = 1; q < CPS; ++q) {
                const float w = tval[t][q];
                if (w < mv) { mv = w; mp = q; }
              }
              minval = mv; minpos = mp;
            }
          } else if (v > minval) {
            tval[t][minpos] = v;
            tidx[t][minpos] = c0 + c;
            float mv = tval[t][0];
            int mp = 0;
#pragma unroll
            for (int q = 1; q < CPS; ++q) {
              const float w = tval[t][q];
              if (w < mv) { mv = w; mp = q; }
            }
            minval = mv; minpos = mp;
          }
        }
      }
      __syncthreads();
    }
  }

  if (t < 128 && (r0 + t) < N_NODES) {
    int* dst = cand + (size_t)(r0 + t) * NCAND + blockIdx.y * CPS;
#pragma unroll
    for (int q = 0; q < CPS; ++q) dst[q] = tidx[t][q];
  }
}

// -------------------- phase 2: exact f64 rescoring + stable top-10 --------------------
__global__ void k_phase2(const float* __restrict__ x, const double* __restrict__ rinv,
                         const int* __restrict__ cand, int* __restrict__ nb) {
  const int i = blockIdx.x;
  const int t = threadIdx.x;  // 256
  __shared__ float xi[FEAT];
  __shared__ double svals[NCAND];
  __shared__ int cidx[NCAND];
  for (int k = t; k < FEAT; k += 256) xi[k] = x[(size_t)i * FEAT + k];
  __syncthreads();
  const int c = t >> 1;
  const int part = t & 1;
  const int ci = cand[(size_t)i * NCAND + c];
  const float* xc = x + (size_t)ci * FEAT + part * 256;
  const float* xip = xi + part * 256;
  double s = 0.0;
  for (int k = 0; k < 256; k += 4) {
    const float4 a = *(const float4*)(xip + k);
    const float4 b = *(const float4*)(xc + k);
    s += (double)a.x * (double)b.x;
    s += (double)a.y * (double)b.y;
    s += (double)a.z * (double)b.z;
    s += (double)a.w * (double)b.w;
  }
  s += __shfl_down(s, 1);
  if (part == 0) {
    svals[c] = s * rinv[i] * rinv[ci];
    cidx[c] = ci;
  }
  __syncthreads();
  if (t == 0) {
    for (int r = 0; r < KTOP; ++r) {
      double best = -1e300;
      int bi = 0x7fffffff, bslot = 0;
      for (int q = 0; q < NCAND; ++q) {
        const double v = svals[q];
        const int id = cidx[q];
        if (v > best || (v == best && id < bi)) { best = v; bi = id; bslot = q; }
      }
      svals[bslot] = -1e301;
      if (r >= 1) nb[(size_t)i * NNB + (r - 1)] = bi;
    }
  }
}

// -------------------- CSR build helpers --------------------
__global__ void k_zero(int* __restrict__ p, int n) {
  const int i = blockIdx.x * blockDim.x + threadIdx.x;
  if (i < n) p[i] = 0;
}

__global__ void k_count(const int* __restrict__ dsts, int ne, int* __restrict__ cnt) {
  const int e = blockIdx.x * blockDim.x + threadIdx.x;
  if (e < ne) atomicAdd(&cnt[dsts[e]], 1);
}

__global__ void k_scan(const int* __restrict__ cnt, int n, int* __restrict__ off,
                       int* __restrict__ cur, float* __restrict__ dinv) {
  __shared__ int buf[1024];
  __shared__ int base_s;
  const int t = threadIdx.x;
  if (t == 0) base_s = 0;
  __syncthreads();
  for (int b0 = 0; b0 < n; b0 += 1024) {
    const int i = b0 + t;
    const int v = (i < n) ? cnt[i] : 0;
    buf[t] = v;
    __syncthreads();
    for (int o = 1; o < 1024; o <<= 1) {
      const int add = (t >= o) ? buf[t - o] : 0;
      __syncthreads();
      buf[t] += add;
      __syncthreads();
    }
    const int incl = buf[t];
    const int base = base_s;
    if (i < n) {
      const int excl = base + incl - v;
      off[i] = excl;
      cur[i] = excl;
      dinv[i] = rsqrtf((float)(v + 1));
    }
    __syncthreads();
    if (t == 1023) base_s = base + buf[1023];
    __syncthreads();
  }
  if (t == 0) off[n] = base_s;
}

__global__ void k_scatter_s(const int* __restrict__ src, const int* __restrict__ dst, int ne,
                            int* __restrict__ cur, int* __restrict__ csr) {
  const int e = blockIdx.x * blockDim.x + threadIdx.x;
  if (e < ne) {
    const int p = atomicAdd(&cur[dst[e]], 1);
    csr[p] = src[e];
  }
}

__global__ void k_scatter_t(const int* __restrict__ nb, int* __restrict__ cur,
                            int* __restrict__ csr) {
  const int e = blockIdx.x * blockDim.x + threadIdx.x;
  if (e < N_NODES * NNB) {
    const int i = e / NNB;
    const int v = nb[e];
    const int p = atomicAdd(&cur[v], 1);
    csr[p] = i;
  }
}

// -------------------- generic f32 GEMM: C[MxN] = A[MxK] @ B[KxN] --------------------
#define GBM 64
#define GBN 64
#define GBK 16
__global__ __launch_bounds__(256) void k_gemm(const float* __restrict__ A,
                                              const float* __restrict__ B,
                                              float* __restrict__ C, int M, int K, int N) {
  __shared__ float As[GBK][GBM + 4];
  __shared__ float Bs[GBK][GBN + 4];
  const int m0 = blockIdx.x * GBM, n0 = blockIdx.y * GBN;
  const int t = threadIdx.x;
  const int ty = t >> 4, tx = t & 15;
  float acc[4][4] = {};
  for (int k0 = 0; k0 < K; k0 += GBK) {
    {
      const int r = t >> 2, kq = (t & 3) * 4;
      const int gm = min(m0 + r, M - 1);
      const float4 v = *(const float4*)(A + (size_t)gm * K + k0 + kq);
      As[kq + 0][r] = v.x;
      As[kq + 1][r] = v.y;
      As[kq + 2][r] = v.z;
      As[kq + 3][r] = v.w;
      const int kk = t >> 4, nq = (t & 15) * 4;
      const float4 w = *(const float4*)(B + (size_t)(k0 + kk) * N + n0 + nq);
      *(float4*)&Bs[kk][nq] = w;
    }
    __syncthreads();
#pragma unroll
    for (int k = 0; k < GBK; ++k) {
      float a[4], b[4];
      *(float4*)&a[0] = *(const float4*)&As[k][ty * 4];
      *(float4*)&b[0] = *(const float4*)&Bs[k][tx * 4];
#pragma unroll
      for (int i = 0; i < 4; ++i)
#pragma unroll
        for (int j = 0; j < 4; ++j) acc[i][j] += a[i] * b[j];
    }
    __syncthreads();
  }
#pragma unroll
  for (int i = 0; i < 4; ++i) {
    const int gm = m0 + ty * 4 + i;
    if (gm < M) {
#pragma unroll
      for (int j = 0; j < 4; ++j) C[(size_t)gm * N + n0 + tx * 4 + j] = acc[i][j];
    }
  }
}

// -------------------- GCN aggregation: out[v] = dinv[v]*(h[v]*dinv[v] + sum h[s]*dinv[s]) + b --------------------
__global__ void k_agg(const float* __restrict__ h, const float* __restrict__ bias,
                      const float* __restrict__ dinv, const int* __restrict__ off,
                      const int* __restrict__ csr, float* __restrict__ out, int C,
                      int do_relu) {
  const int v = blockIdx.x;
  const int c = threadIdx.x;  // blockDim == C
  const float dv = dinv[v];
  float acc = h[(size_t)v * C + c] * dv;
  const int s0 = off[v], s1 = off[v + 1];
  for (int e = s0; e < s1; ++e) {
    const int s = csr[e];
    acc += h[(size_t)s * C + c] * dinv[s];
  }
  acc = acc * dv + bias[c];
  if (do_relu) acc = fmaxf(acc, 0.f);
  out[(size_t)v * C + c] = acc;
}

// -------------------- fusion + Student-t soft assignment --------------------
__global__ void k_fuse(const float* __restrict__ zs, const float* __restrict__ zt,
                       const float* __restrict__ fw, const float* __restrict__ cent,
                       float* __restrict__ out_z, float* __restrict__ out_q) {
  const int v = blockIdx.x;
  const int t = threadIdx.x;  // 128
  __shared__ float zsh[EMB];
  __shared__ float cs[NC][EMB];
  __shared__ float qv[NC];
  __shared__ float qs;
  for (int k = t; k < NC * EMB; k += 128) ((float*)cs)[k] = cent[k];
  const float beta = 1.f / (1.f + expf(-fw[0]));
  const float z = beta * zs[(size_t)v * EMB + t] + (1.f - beta) * zt[(size_t)v * EMB + t];
  out_z[(size_t)v * EMB + t] = z;
  zsh[t] = z;
  __syncthreads();
  if (t < NC) {
    float s = 0.f;
    for (int c = 0; c < EMB; ++c) {
      const float d = zsh[c] - cs[t][c];
      s += d * d;
    }
    qv[t] = 1.f / (1.f + s);
  }
  __syncthreads();
  if (t == 0) {
    float s = 0.f;
    for (int k = 0; k < NC; ++k) s += qv[k];
    qs = s;
  }
  __syncthreads();
  if (t < NC) out_q[(size_t)v * NC + t] = qv[t] / qs;
}

extern "C" void kernel_launch(void* const* d_in, const int* in_sizes, int n_in, void* d_out,
                              int out_size, void* d_ws, size_t ws_size, hipStream_t stream) {
  const float* x = (const float*)d_in[0];
  const int* ei = (const int*)d_in[1];  // [2][NE]: src then dst
  const float* W_s1 = (const float*)d_in[2];
  const float* b_s1 = (const float*)d_in[3];
  const float* W_s2 = (const float*)d_in[4];
  const float* b_s2 = (const float*)d_in[5];
  const float* W_t1 = (const float*)d_in[6];
  const float* b_t1 = (const float*)d_in[7];
  const float* W_t2 = (const float*)d_in[8];
  const float* b_t2 = (const float*)d_in[9];
  const float* fw = (const float*)d_in[10];
  const float* cent = (const float*)d_in[11];
  float* out_z = (float*)d_out;
  float* out_q = out_z + (size_t)N_NODES * EMB;

  char* w = (char*)d_ws;
  size_t o = 0;
  auto alloc = [&](size_t bytes) -> void* {
    void* p = w + o;
    o += (bytes + 255) & ~(size_t)255;
    return p;
  };
  // region reused: xn (phase1 only) -> h1_s | h1_t (after phase1)
  float* xn = (float*)alloc((size_t)N_NODES * FEAT * 4);
  float* h1_s = xn;
  float* h1_t = xn + (size_t)N_NODES * HID;
  double* rinv = (double*)alloc((size_t)N_NODES * 8);
  // region reused: cand (phases 1-2) -> r1_s (after phase2)
  float* r1_s = (float*)alloc((size_t)N_NODES * HID * 4);
  float* r1_t = (float*)alloc((size_t)N_NODES * HID * 4);
  int* cand = (int*)r1_s;  // 10000*128*4 = 5.12 MB < 10.24 MB
  float* h2_s = (float*)alloc((size_t)N_NODES * EMB * 4);
  float* h2_t = (float*)alloc((size_t)N_NODES * EMB * 4);
  float* z_s = (float*)alloc((size_t)N_NODES * EMB * 4);
  float* z_t = (float*)alloc((size_t)N_NODES * EMB * 4);
  int* nb = (int*)alloc((size_t)N_NODES * NNB * 4);
  int* cnt_s = (int*)alloc((size_t)N_NODES * 4);
  int* off_s = (int*)alloc((size_t)(N_NODES + 1) * 4);
  int* cur_s = (int*)alloc((size_t)N_NODES * 4);
  float* dinv_s = (float*)alloc((size_t)N_NODES * 4);
  int* cnt_t = (int*)alloc((size_t)N_NODES * 4);
  int* off_t = (int*)alloc((size_t)(N_NODES + 1) * 4);
  int* cur_t = (int*)alloc((size_t)N_NODES * 4);
  float* dinv_t = (float*)alloc((size_t)N_NODES * 4);
  int* csr_s = (int*)alloc((size_t)NE_EDGES * 4);
  int* csr_t = (int*)alloc((size_t)N_NODES * NNB * 4);

  const int* e_src = ei;
  const int* e_dst = ei + NE_EDGES;

  // 1. norms + normalized features
  k_norms<<<N_NODES, 128, 0, stream>>>(x, xn, rinv);
  // 2. zero degree counters
  k_zero<<<(N_NODES + 255) / 256, 256, 0, stream>>>(cnt_s, N_NODES);
  k_zero<<<(N_NODES + 255) / 256, 256, 0, stream>>>(cnt_t, N_NODES);
  // 3. structural in-degree
  k_count<<<(NE_EDGES + 255) / 256, 256, 0, stream>>>(e_dst, NE_EDGES, cnt_s);
  // 4. phase-1 candidates (f32 sims, top-16 per 1/8 column split)
  {
    dim3 grid((N_NODES + P1_ROWS - 1) / P1_ROWS, NSPLIT);
    k_phase1<<<grid, 256, 0, stream>>>(xn, cand);
  }
  // 5. phase-2 exact f64 rescore -> 9 neighbors per node
  k_phase2<<<N_NODES, 256, 0, stream>>>(x, rinv, cand, nb);
  // 6. topology in-degree
  k_count<<<(N_NODES * NNB + 255) / 256, 256, 0, stream>>>(nb, N_NODES * NNB, cnt_t);
  // 7. scans (offsets, cursors, dinv)
  k_scan<<<1, 1024, 0, stream>>>(cnt_s, N_NODES, off_s, cur_s, dinv_s);
  k_scan<<<1, 1024, 0, stream>>>(cnt_t, N_NODES, off_t, cur_t, dinv_t);
  // 8. CSR scatter
  k_scatter_s<<<(NE_EDGES + 255) / 256, 256, 0, stream>>>(e_src, e_dst, NE_EDGES, cur_s, csr_s);
  k_scatter_t<<<(N_NODES * NNB + 255) / 256, 256, 0, stream>>>(nb, cur_t, csr_t);
  // 9. layer-1 GEMMs (writes into the xn region; xn is dead after phase 1)
  {
    dim3 g1((N_NODES + GBM - 1) / GBM, HID / GBN);
    k_gemm<<<g1, 256, 0, stream>>>(x, W_s1, h1_s, N_NODES, FEAT, HID);
    k_gemm<<<g1, 256, 0, stream>>>(x, W_t1, h1_t, N_NODES, FEAT, HID);
  }
  // 10. layer-1 aggregation + bias + relu
  k_agg<<<N_NODES, HID, 0, stream>>>(h1_s, b_s1, dinv_s, off_s, csr_s, r1_s, HID, 1);
  k_agg<<<N_NODES, HID, 0, stream>>>(h1_t, b_t1, dinv_t, off_t, csr_t, r1_t, HID, 1);
  // 11. layer-2 GEMMs
  {
    dim3 g2((N_NODES + GBM - 1) / GBM, EMB / GBN);
    k_gemm<<<g2, 256, 0, stream>>>(r1_s, W_s2, h2_s, N_NODES, HID, EMB);
    k_gemm<<<g2, 256, 0, stream>>>(r1_t, W_t2, h2_t, N_NODES, HID, EMB);
  }
  // 12. layer-2 aggregation + bias
  k_agg<<<N_NODES, EMB, 0, stream>>>(h2_s, b_s2, dinv_s, off_s, csr_s, z_s, EMB, 0);
  k_agg<<<N_NODES, EMB, 0, stream>>>(h2_t, b_t2, dinv_t, off_t, csr_t, z_t, EMB, 0);
  // 13. fusion + soft assignment
  k_fuse<<<N_NODES, 128, 0, stream>>>(z_s, z_t, fw, cent, out_z, out_q);
}

// Round 2
// 1535.361 us; speedup vs baseline: 3.2403x; 3.2403x over previous
//
#include <hip/hip_runtime.h>
#include <math.h>

#define N_NODES 10000
#define FEAT 512
#define HID 256
#define EMB 128
#define NC 10
#define NE_EDGES 160000
#define KTOP 10
#define NNB 9

#define NSPLIT 8
#define CPS 16
#define NCAND (NSPLIT * CPS)   // 128
#define SPLITW 1250
#define NCHUNK 20              // 20*64 >= 1250

typedef __attribute__((ext_vector_type(8))) short short8;
typedef __attribute__((ext_vector_type(4))) float f32x4;

__device__ __forceinline__ unsigned short f2bf(float f) {
  unsigned int u = __float_as_uint(f);
  u = (u + 0x7fffu + ((u >> 16) & 1u)) >> 16;
  return (unsigned short)u;
}
__device__ __forceinline__ float bf2f(unsigned short b) {
  return __uint_as_float(((unsigned int)b) << 16);
}

// -------------------- row norms -> bf16 normalized rows + f64 inv norms --------------------
__global__ void k_norms(const float* __restrict__ x, unsigned short* __restrict__ xnb,
                        double* __restrict__ rinv) {
  const int row = blockIdx.x;
  const int t = threadIdx.x;  // 128
  const float* xr = x + (size_t)row * FEAT;
  double s = 0.0;
  for (int k = t; k < FEAT; k += 128) { const double v = (double)xr[k]; s += v * v; }
  __shared__ double red[128];
  red[t] = s;
  __syncthreads();
  for (int o = 64; o > 0; o >>= 1) {
    if (t < o) red[t] += red[t + o];
    __syncthreads();
  }
  const double inv = 1.0 / fmax(sqrt(red[0]), 1e-12);
  const float finv = (float)inv;
  for (int k = t; k < FEAT; k += 128) xnb[(size_t)row * FEAT + k] = f2bf(xr[k] * finv);
  if (t == 0) rinv[row] = inv;
}

// -------------------- phase 1: bf16 MFMA sims + top-16 candidates per split --------------------
// 128 rows x 1250 cols per block, processed in 20 chunks of 64 cols.
// LDS: As 16K + Bs 8K + simb 16.9K + tval 8.7K + tidx 8.7K = 58.9 KB
__global__ __launch_bounds__(256) void k_phase1(const unsigned short* __restrict__ xnb,
                                                int* __restrict__ cand) {
  __shared__ __align__(16) unsigned short As[128 * 64];
  __shared__ __align__(16) unsigned short Bs[64 * 64];
  __shared__ unsigned short simb[128 * 66];
  __shared__ float tval[128][17];
  __shared__ int tidx[128][17];

  const int t = threadIdx.x;
  const int lane = t & 63;
  const int wave = t >> 6;
  const int wr = wave >> 1;  // row half (0..1) -> 64 rows
  const int wc = wave & 1;   // col half (0..1) -> 32 cols
  const int lr = lane & 15;
  const int lk = lane >> 4;

  const int r0 = blockIdx.x * 128;
  const int cstart = blockIdx.y * SPLITW;
  const int cend = min(cstart + SPLITW, N_NODES);

  int cnt = 0, minpos = 0;
  float minval = -3e38f;

  for (int ch = 0; ch < NCHUNK; ++ch) {
    const int c0 = cstart + ch * 64;
    const int cmax = min(64, cend - c0);
    f32x4 acc[4][2];
#pragma unroll
    for (int m = 0; m < 4; ++m)
#pragma unroll
      for (int n = 0; n < 2; ++n) acc[m][n] = (f32x4){0.f, 0.f, 0.f, 0.f};

    for (int k0 = 0; k0 < FEAT; k0 += 64) {
      __syncthreads();
      // stage A tile 128x64 (1024 16B slots), XOR-swizzled: slot(r, kb) holds data (r, kb^(r&7))
#pragma unroll
      for (int it = 0; it < 4; ++it) {
        const int s = it * 256 + t;
        const int r = s >> 3, kb = s & 7;
        const int gr = min(r0 + r, N_NODES - 1);
        const uint4 v = *(const uint4*)(xnb + (size_t)gr * FEAT + k0 + kb * 8);
        *(uint4*)((char*)As + (((r << 3) | (kb ^ (r & 7))) << 4)) = v;
      }
      // stage B tile 64x64 (512 slots)
#pragma unroll
      for (int it = 0; it < 2; ++it) {
        const int s = it * 256 + t;
        const int r = s >> 3, kb = s & 7;
        const int gc = min(c0 + r, N_NODES - 1);
        const uint4 v = *(const uint4*)(xnb + (size_t)gc * FEAT + k0 + kb * 8);
        *(uint4*)((char*)Bs + (((r << 3) | (kb ^ (r & 7))) << 4)) = v;
      }
      __syncthreads();
#pragma unroll
      for (int kk = 0; kk < 2; ++kk) {
        const int kbw = kk * 4 + lk;
        short8 a[4], b[2];
#pragma unroll
        for (int m = 0; m < 4; ++m) {
          const int r = wr * 64 + m * 16 + lr;
          a[m] = *(const short8*)((const char*)As + (((r << 3) | (kbw ^ (r & 7))) << 4));
        }
#pragma unroll
        for (int n = 0; n < 2; ++n) {
          const int r = wc * 32 + n * 16 + lr;
          b[n] = *(const short8*)((const char*)Bs + (((r << 3) | (kbw ^ (r & 7))) << 4));
        }
#pragma unroll
        for (int m = 0; m < 4; ++m)
#pragma unroll
          for (int n = 0; n < 2; ++n)
            acc[m][n] = __builtin_amdgcn_mfma_f32_16x16x32_bf16(a[m], b[n], acc[m][n], 0, 0, 0);
      }
    }

    // dump acc to simb as bf16. C/D layout: col = lane&15, row = (lane>>4)*4 + reg
#pragma unroll
    for (int m = 0; m < 4; ++m) {
      const int rbase = wr * 64 + m * 16 + lk * 4;
#pragma unroll
      for (int n = 0; n < 2; ++n) {
        const int c = wc * 32 + n * 16 + lr;
#pragma unroll
        for (int q = 0; q < 4; ++q) simb[(rbase + q) * 66 + c] = f2bf(acc[m][n][q]);
      }
    }
    __syncthreads();

    // selection: thread t owns row t
    if (t < 128) {
      for (int c = 0; c < cmax; ++c) {
        const float v = bf2f(simb[t * 66 + c]);
        if (cnt < CPS) {
          tval[t][cnt] = v;
          tidx[t][cnt] = c0 + c;
          ++cnt;
          if (cnt == CPS) {
            float mv = tval[t][0];
            int mp = 0;
#pragma unroll
            for (int q = 1; q < CPS; ++q) {
              const float w = tval[t][q];
              if (w < mv) { mv = w; mp = q; }
            }
            minval = mv; minpos = mp;
          }
        } else if (v > minval) {
          tval[t][minpos] = v;
          tidx[t][minpos] = c0 + c;
          float mv = tval[t][0];
          int mp = 0;
#pragma unroll
          for (int q = 1; q < CPS; ++q) {
            const float w = tval[t][q];
            if (w < mv) { mv = w; mp = q; }
          }
          minval = mv; minpos = mp;
        }
      }
    }
    __syncthreads();
  }

  if (t < 128 && (r0 + t) < N_NODES) {
    int* dst = cand + (size_t)(r0 + t) * NCAND + blockIdx.y * CPS;
#pragma unroll
    for (int q = 0; q < CPS; ++q) dst[q] = tidx[t][q];
  }
}

// -------------------- phase 2: exact f64 rescoring, coalesced + parallel top-10 --------------------
__global__ __launch_bounds__(256) void k_phase2(const float* __restrict__ x,
                                                const double* __restrict__ rinv,
                                                const int* __restrict__ cand,
                                                int* __restrict__ nb) {
  const int i = blockIdx.x;
  const int t = threadIdx.x;
  const int lane = t & 63;
  const int wave = t >> 6;
  __shared__ float xi[FEAT];
  __shared__ double sv[NCAND];
  __shared__ int sidx[NCAND];
  __shared__ double wmax[2];
  __shared__ int wmaxi[2];

  xi[t] = x[(size_t)i * FEAT + t];
  xi[t + 256] = x[(size_t)i * FEAT + t + 256];
  __syncthreads();

  const double ri = rinv[i];
  const float4 v0 = *(const float4*)(xi + lane * 8);
  const float4 v1 = *(const float4*)(xi + lane * 8 + 4);

  for (int cc = 0; cc < 32; ++cc) {
    const int c = wave * 32 + cc;
    const int ci = cand[(size_t)i * NCAND + c];
    const float4* xr = (const float4*)(x + (size_t)ci * FEAT);
    const float4 u0 = xr[lane * 2];
    const float4 u1 = xr[lane * 2 + 1];
    double s = (double)u0.x * (double)v0.x + (double)u0.y * (double)v0.y +
               (double)u0.z * (double)v0.z + (double)u0.w * (double)v0.w +
               (double)u1.x * (double)v1.x + (double)u1.y * (double)v1.y +
               (double)u1.z * (double)v1.z + (double)u1.w * (double)v1.w;
#pragma unroll
    for (int off = 1; off < 64; off <<= 1) s += __shfl_xor(s, off);
    if (lane == 0) {
      sv[c] = s * ri * rinv[ci];
      sidx[c] = ci;
    }
  }
  __syncthreads();

  double v = -1e308;
  int id = 0x7fffffff;
  if (t < NCAND) { v = sv[t]; id = sidx[t]; }

  for (int r = 0; r < KTOP; ++r) {
    double bv = v;
    int bi = id;
#pragma unroll
    for (int off = 1; off < 64; off <<= 1) {
      const double ov = __shfl_xor(bv, off);
      const int oi = __shfl_xor(bi, off);
      if (ov > bv || (ov == bv && oi < bi)) { bv = ov; bi = oi; }
    }
    if (lane == 0 && wave < 2) { wmax[wave] = bv; wmaxi[wave] = bi; }
    __syncthreads();
    const double g0 = wmax[0], g1 = wmax[1];
    const int i0 = wmaxi[0], i1 = wmaxi[1];
    const bool take1 = (g1 > g0) || (g1 == g0 && i1 < i0);
    const int gi = take1 ? i1 : i0;
    if (r >= 1 && t == 0) nb[(size_t)i * NNB + (r - 1)] = gi;
    if (id == gi) v = -1e308;
    __syncthreads();
  }
}

// -------------------- CSR build helpers --------------------
__global__ void k_zero(int* __restrict__ p, int n) {
  const int i = blockIdx.x * blockDim.x + threadIdx.x;
  if (i < n) p[i] = 0;
}

__global__ void k_count(const int* __restrict__ dsts, int ne, int* __restrict__ cnt) {
  const int e = blockIdx.x * blockDim.x + threadIdx.x;
  if (e < ne) atomicAdd(&cnt[dsts[e]], 1);
}

__global__ void k_scan(const int* __restrict__ cnt, int n, int* __restrict__ off,
                       int* __restrict__ cur, float* __restrict__ dinv) {
  __shared__ int buf[1024];
  __shared__ int base_s;
  const int t = threadIdx.x;
  if (t == 0) base_s = 0;
  __syncthreads();
  for (int b0 = 0; b0 < n; b0 += 1024) {
    const int i = b0 + t;
    const int v = (i < n) ? cnt[i] : 0;
    buf[t] = v;
    __syncthreads();
    for (int o = 1; o < 1024; o <<= 1) {
      const int add = (t >= o) ? buf[t - o] : 0;
      __syncthreads();
      buf[t] += add;
      __syncthreads();
    }
    const int incl = buf[t];
    const int base = base_s;
    if (i < n) {
      const int excl = base + incl - v;
      off[i] = excl;
      cur[i] = excl;
      dinv[i] = rsqrtf((float)(v + 1));
    }
    __syncthreads();
    if (t == 1023) base_s = base + buf[1023];
    __syncthreads();
  }
  if (t == 0) off[n] = base_s;
}

__global__ void k_scatter_s(const int* __restrict__ src, const int* __restrict__ dst, int ne,
                            int* __restrict__ cur, int* __restrict__ csr) {
  const int e = blockIdx.x * blockDim.x + threadIdx.x;
  if (e < ne) {
    const int p = atomicAdd(&cur[dst[e]], 1);
    csr[p] = src[e];
  }
}

__global__ void k_scatter_t(const int* __restrict__ nb, int* __restrict__ cur,
                            int* __restrict__ csr) {
  const int e = blockIdx.x * blockDim.x + threadIdx.x;
  if (e < N_NODES * NNB) {
    const int i = e / NNB;
    const int v = nb[e];
    const int p = atomicAdd(&cur[v], 1);
    csr[p] = i;
  }
}

// -------------------- generic f32 GEMM: C[MxN] = A[MxK] @ B[KxN] --------------------
#define GBM 64
#define GBN 64
#define GBK 16
__global__ __launch_bounds__(256) void k_gemm(const float* __restrict__ A,
                                              const float* __restrict__ B,
                                              float* __restrict__ C, int M, int K, int N) {
  __shared__ float As[GBK][GBM + 4];
  __shared__ float Bs[GBK][GBN + 4];
  const int m0 = blockIdx.x * GBM, n0 = blockIdx.y * GBN;
  const int t = threadIdx.x;
  const int ty = t >> 4, tx = t & 15;
  float acc[4][4] = {};
  for (int k0 = 0; k0 < K; k0 += GBK) {
    {
      const int r = t >> 2, kq = (t & 3) * 4;
      const int gm = min(m0 + r, M - 1);
      const float4 v = *(const float4*)(A + (size_t)gm * K + k0 + kq);
      As[kq + 0][r] = v.x;
      As[kq + 1][r] = v.y;
      As[kq + 2][r] = v.z;
      As[kq + 3][r] = v.w;
      const int kk = t >> 4, nq = (t & 15) * 4;
      const float4 w = *(const float4*)(B + (size_t)(k0 + kk) * N + n0 + nq);
      *(float4*)&Bs[kk][nq] = w;
    }
    __syncthreads();
#pragma unroll
    for (int k = 0; k < GBK; ++k) {
      float a[4], b[4];
      *(float4*)&a[0] = *(const float4*)&As[k][ty * 4];
      *(float4*)&b[0] = *(const float4*)&Bs[k][tx * 4];
#pragma unroll
      for (int i = 0; i < 4; ++i)
#pragma unroll
        for (int j = 0; j < 4; ++j) acc[i][j] += a[i] * b[j];
    }
    __syncthreads();
  }
#pragma unroll
  for (int i = 0; i < 4; ++i) {
    const int gm = m0 + ty * 4 + i;
    if (gm < M) {
#pragma unroll
      for (int j = 0; j < 4; ++j) C[(size_t)gm * N + n0 + tx * 4 + j] = acc[i][j];
    }
  }
}

// -------------------- GCN aggregation --------------------
__global__ void k_agg(const float* __restrict__ h, const float* __restrict__ bias,
                      const float* __restrict__ dinv, const int* __restrict__ off,
                      const int* __restrict__ csr, float* __restrict__ out, int C,
                      int do_relu) {
  const int v = blockIdx.x;
  const int c = threadIdx.x;
  const float dv = dinv[v];
  float acc = h[(size_t)v * C + c] * dv;
  const int s0 = off[v], s1 = off[v + 1];
  for (int e = s0; e < s1; ++e) {
    const int s = csr[e];
    acc += h[(size_t)s * C + c] * dinv[s];
  }
  acc = acc * dv + bias[c];
  if (do_relu) acc = fmaxf(acc, 0.f);
  out[(size_t)v * C + c] = acc;
}

// -------------------- fusion + Student-t soft assignment --------------------
__global__ void k_fuse(const float* __restrict__ zs, const float* __restrict__ zt,
                       const float* __restrict__ fw, const float* __restrict__ cent,
                       float* __restrict__ out_z, float* __restrict__ out_q) {
  const int v = blockIdx.x;
  const int t = threadIdx.x;  // 128
  __shared__ float zsh[EMB];
  __shared__ float cs[NC][EMB];
  __shared__ float qv[NC];
  __shared__ float qs;
  for (int k = t; k < NC * EMB; k += 128) ((float*)cs)[k] = cent[k];
  const float beta = 1.f / (1.f + expf(-fw[0]));
  const float z = beta * zs[(size_t)v * EMB + t] + (1.f - beta) * zt[(size_t)v * EMB + t];
  out_z[(size_t)v * EMB + t] = z;
  zsh[t] = z;
  __syncthreads();
  if (t < NC) {
    float s = 0.f;
    for (int c = 0; c < EMB; ++c) {
      const float d = zsh[c] - cs[t][c];
      s += d * d;
    }
    qv[t] = 1.f / (1.f + s);
  }
  __syncthreads();
  if (t == 0) {
    float s = 0.f;
    for (int k = 0; k < NC; ++k) s += qv[k];
    qs = s;
  }
  __syncthreads();
  if (t < NC) out_q[(size_t)v * NC + t] = qv[t] / qs;
}

extern "C" void kernel_launch(void* const* d_in, const int* in_sizes, int n_in, void* d_out,
                              int out_size, void* d_ws, size_t ws_size, hipStream_t stream) {
  const float* x = (const float*)d_in[0];
  const int* ei = (const int*)d_in[1];
  const float* W_s1 = (const float*)d_in[2];
  const float* b_s1 = (const float*)d_in[3];
  const float* W_s2 = (const float*)d_in[4];
  const float* b_s2 = (const float*)d_in[5];
  const float* W_t1 = (const float*)d_in[6];
  const float* b_t1 = (const float*)d_in[7];
  const float* W_t2 = (const float*)d_in[8];
  const float* b_t2 = (const float*)d_in[9];
  const float* fw = (const float*)d_in[10];
  const float* cent = (const float*)d_in[11];
  float* out_z = (float*)d_out;
  float* out_q = out_z + (size_t)N_NODES * EMB;

  char* w = (char*)d_ws;
  size_t o = 0;
  auto alloc = [&](size_t bytes) -> void* {
    void* p = w + o;
    o += (bytes + 255) & ~(size_t)255;
    return p;
  };
  // xnb (phase1 input) -> h1_s after phase1 completes
  unsigned short* xnb = (unsigned short*)alloc((size_t)N_NODES * FEAT * 2);  // 10.24 MB
  float* h1_s = (float*)xnb;                                                 // 10.24 MB (alias)
  double* rinv = (double*)alloc((size_t)N_NODES * 8);
  // cand (phase1/2) -> r1_s after phase2 completes
  float* r1_s = (float*)alloc((size_t)N_NODES * HID * 4);
  int* cand = (int*)r1_s;  // 5.12 MB < 10.24 MB
  float* r1_t = (float*)alloc((size_t)N_NODES * HID * 4);
  float* h1_t = (float*)alloc((size_t)N_NODES * HID * 4);
  float* h2_s = (float*)alloc((size_t)N_NODES * EMB * 4);
  float* h2_t = (float*)alloc((size_t)N_NODES * EMB * 4);
  float* z_s = (float*)alloc((size_t)N_NODES * EMB * 4);
  float* z_t = (float*)alloc((size_t)N_NODES * EMB * 4);
  int* nb = (int*)alloc((size_t)N_NODES * NNB * 4);
  int* cnt_s = (int*)alloc((size_t)N_NODES * 4);
  int* off_s = (int*)alloc((size_t)(N_NODES + 1) * 4);
  int* cur_s = (int*)alloc((size_t)N_NODES * 4);
  float* dinv_s = (float*)alloc((size_t)N_NODES * 4);
  int* cnt_t = (int*)alloc((size_t)N_NODES * 4);
  int* off_t = (int*)alloc((size_t)(N_NODES + 1) * 4);
  int* cur_t = (int*)alloc((size_t)N_NODES * 4);
  float* dinv_t = (float*)alloc((size_t)N_NODES * 4);
  int* csr_s = (int*)alloc((size_t)NE_EDGES * 4);
  int* csr_t = (int*)alloc((size_t)N_NODES * NNB * 4);

  const int* e_src = ei;
  const int* e_dst = ei + NE_EDGES;

  // 1. norms -> bf16 normalized rows + f64 inv norms
  k_norms<<<N_NODES, 128, 0, stream>>>(x, xnb, rinv);
  // 2. degree counters
  k_zero<<<(N_NODES + 255) / 256, 256, 0, stream>>>(cnt_s, N_NODES);
  k_zero<<<(N_NODES + 255) / 256, 256, 0, stream>>>(cnt_t, N_NODES);
  k_count<<<(NE_EDGES + 255) / 256, 256, 0, stream>>>(e_dst, NE_EDGES, cnt_s);
  // 3. phase-1 MFMA candidates
  {
    dim3 grid((N_NODES + 127) / 128, NSPLIT);
    k_phase1<<<grid, 256, 0, stream>>>(xnb, cand);
  }
  // 4. phase-2 exact f64 rescore -> 9 neighbors
  k_phase2<<<N_NODES, 256, 0, stream>>>(x, rinv, cand, nb);
  // 5. topology degrees + scans + scatter
  k_count<<<(N_NODES * NNB + 255) / 256, 256, 0, stream>>>(nb, N_NODES * NNB, cnt_t);
  k_scan<<<1, 1024, 0, stream>>>(cnt_s, N_NODES, off_s, cur_s, dinv_s);
  k_scan<<<1, 1024, 0, stream>>>(cnt_t, N_NODES, off_t, cur_t, dinv_t);
  k_scatter_s<<<(NE_EDGES + 255) / 256, 256, 0, stream>>>(e_src, e_dst, NE_EDGES, cur_s, csr_s);
  k_scatter_t<<<(N_NODES * NNB + 255) / 256, 256, 0, stream>>>(nb, cur_t, csr_t);
  // 6. layer-1 GEMMs (h1_s aliases xnb: safe, phase1/2 already done)
  {
    dim3 g1((N_NODES + GBM - 1) / GBM, HID / GBN);
    k_gemm<<<g1, 256, 0, stream>>>(x, W_s1, h1_s, N_NODES, FEAT, HID);
    k_gemm<<<g1, 256, 0, stream>>>(x, W_t1, h1_t, N_NODES, FEAT, HID);
  }
  // 7. layer-1 aggregation + relu (r1_s overwrites cand: safe, phase2 done)
  k_agg<<<N_NODES, HID, 0, stream>>>(h1_s, b_s1, dinv_s, off_s, csr_s, r1_s, HID, 1);
  k_agg<<<N_NODES, HID, 0, stream>>>(h1_t, b_t1, dinv_t, off_t, csr_t, r1_t, HID, 1);
  // 8. layer-2 GEMMs
  {
    dim3 g2((N_NODES + GBM - 1) / GBM, EMB / GBN);
    k_gemm<<<g2, 256, 0, stream>>>(r1_s, W_s2, h2_s, N_NODES, HID, EMB);
    k_gemm<<<g2, 256, 0, stream>>>(r1_t, W_t2, h2_t, N_NODES, HID, EMB);
  }
  // 9. layer-2 aggregation
  k_agg<<<N_NODES, EMB, 0, stream>>>(h2_s, b_s2, dinv_s, off_s, csr_s, z_s, EMB, 0);
  k_agg<<<N_NODES, EMB, 0, stream>>>(h2_t, b_t2, dinv_t, off_t, csr_t, z_t, EMB, 0);
  // 10. fusion + soft assignment
  k_fuse<<<N_NODES, 128, 0, stream>>>(z_s, z_t, fw, cent, out_z, out_q);
}

// Round 3
// 1459.314 us; speedup vs baseline: 3.4091x; 1.0521x over previous
//
#include <hip/hip_runtime.h>
#include <math.h>

#define N_NODES 10000
#define FEAT 512
#define HID 256
#define EMB 128
#define NC 10
#define NE_EDGES 160000
#define KTOP 10
#define NNB 9

#define NSPLIT 8
#define CPS 16
#define NCAND (NSPLIT * CPS)   // 128
#define SPLITW 1250
#define NSEL 32                // candidates rescored in f64
#define NCPAD 10112            // 79*128
#define STRIPE_ROWS 1280       // 10 tile-rows per stripe
#define NSTRIPE 8

typedef __attribute__((ext_vector_type(8))) short short8;
typedef __attribute__((ext_vector_type(4))) float f32x4;

typedef const __attribute__((address_space(1))) unsigned int* gas1_t;
typedef __attribute__((address_space(3))) unsigned int* las3_t;

__device__ __forceinline__ void gload_lds16(const void* g, void* l) {
  __builtin_amdgcn_global_load_lds((gas1_t)g, (las3_t)l, 16, 0, 0);
}

__device__ __forceinline__ unsigned short f2bf(float f) {
  unsigned int u = __float_as_uint(f);
  u = (u + 0x7fffu + ((u >> 16) & 1u)) >> 16;
  return (unsigned short)u;
}
__device__ __forceinline__ float bf2f(unsigned short b) {
  return __uint_as_float(((unsigned int)b) << 16);
}

// -------------------- row norms -> bf16 normalized rows + f64 inv norms --------------------
__global__ void k_norms(const float* __restrict__ x, unsigned short* __restrict__ xnb,
                        double* __restrict__ rinv) {
  const int row = blockIdx.x;
  const int t = threadIdx.x;  // 128
  const float* xr = x + (size_t)row * FEAT;
  double s = 0.0;
  for (int k = t; k < FEAT; k += 128) { const double v = (double)xr[k]; s += v * v; }
  __shared__ double red[128];
  red[t] = s;
  __syncthreads();
  for (int o = 64; o > 0; o >>= 1) {
    if (t < o) red[t] += red[t + o];
    __syncthreads();
  }
  const double inv = 1.0 / fmax(sqrt(red[0]), 1e-12);
  const float finv = (float)inv;
  for (int k = t; k < FEAT; k += 128) xnb[(size_t)row * FEAT + k] = f2bf(xr[k] * finv);
  if (t == 0) rinv[row] = inv;
}

// -------------------- sim GEMM: stripe of C = Xn @ Xn^T (bf16 out) --------------------
// 128x128 tile, BK=32, double-buffered LDS via global_load_lds, 4 waves (2x2 quadrants,
// each wave 4x4 frags of 16x16x32). One barrier per K-step (m97 structure).
__global__ __launch_bounds__(256) void k_simgemm(const unsigned short* __restrict__ xnb,
                                                 unsigned short* __restrict__ sim, int row0) {
  __shared__ __align__(16) char smem[34816];
  unsigned short* As = (unsigned short*)smem;            // [2][128*32]
  unsigned short* Bs = (unsigned short*)(smem + 16384);  // [2][128*32]
  unsigned short* Cs = (unsigned short*)smem;            // [128][136] (reused)

  const int t = threadIdx.x;
  const int lane = t & 63;
  const int w = t >> 6;
  const int lr = lane & 15;
  const int lk = lane >> 4;
  const int wr = (w >> 1) * 64, wc = (w & 1) * 64;
  const int btx = blockIdx.x, by = blockIdx.y;
  const int arow0 = row0 + by * 128;
  const int bcol0 = btx * 128;

  // stage K-slice k0 into buffer b (A rows and B rows are both rows of xnb)
  auto stage = [&](int b, int k0) {
#pragma unroll
    for (int it = 0; it < 2; ++it) {
      const int slot = it * 256 + w * 64 + lane;
      const int r = slot >> 2, q = slot & 3;
      {
        const int gr = min(arow0 + r, N_NODES - 1);
        gload_lds16(xnb + (size_t)gr * FEAT + k0 + q * 8,
                    As + b * 4096 + (it * 256 + w * 64) * 8);
      }
      {
        const int gr = min(bcol0 + r, N_NODES - 1);
        gload_lds16(xnb + (size_t)gr * FEAT + k0 + q * 8,
                    Bs + b * 4096 + (it * 256 + w * 64) * 8);
      }
    }
  };

  f32x4 acc[4][4];
#pragma unroll
  for (int m = 0; m < 4; ++m)
#pragma unroll
    for (int n = 0; n < 4; ++n) acc[m][n] = (f32x4){0.f, 0.f, 0.f, 0.f};

  stage(0, 0);
  __syncthreads();

  int cur = 0;
  const int NT = FEAT / 32;  // 16
  for (int kt = 0; kt < NT; ++kt) {
    if (kt + 1 < NT) stage(cur ^ 1, (kt + 1) * 32);
    const unsigned short* Ab = As + cur * 4096;
    const unsigned short* Bb = Bs + cur * 4096;
    short8 a[4], b[4];
#pragma unroll
    for (int m = 0; m < 4; ++m)
      a[m] = *(const short8*)(Ab + (wr + m * 16 + lr) * 32 + lk * 8);
#pragma unroll
    for (int n = 0; n < 4; ++n)
      b[n] = *(const short8*)(Bb + (wc + n * 16 + lr) * 32 + lk * 8);
#pragma unroll
    for (int m = 0; m < 4; ++m)
#pragma unroll
      for (int n = 0; n < 4; ++n)
        acc[m][n] = __builtin_amdgcn_mfma_f32_16x16x32_bf16(a[m], b[n], acc[m][n], 0, 0, 0);
    __syncthreads();
    cur ^= 1;
  }

  // epilogue: acc -> Cs (bf16) -> coalesced global store
  // C/D layout: col = lane&15, row = (lane>>4)*4 + reg
#pragma unroll
  for (int m = 0; m < 4; ++m) {
    const int rb = wr + m * 16 + lk * 4;
#pragma unroll
    for (int n = 0; n < 4; ++n) {
      const int c = wc + n * 16 + lr;
#pragma unroll
      for (int q = 0; q < 4; ++q) Cs[(rb + q) * 136 + c] = f2bf(acc[m][n][q]);
    }
  }
  __syncthreads();
#pragma unroll
  for (int it = 0; it < 8; ++it) {
    const int slot = it * 256 + t;
    const int r = slot >> 4, q = slot & 15;
    const uint4 v = *(const uint4*)((const char*)Cs + r * 272 + q * 16);
    *(uint4*)(sim + (size_t)(by * 128 + r) * NCPAD + bcol0 + q * 8) = v;
  }
}

// -------------------- selection: per row, per-split (8x1250) top-16 with values --------------------
__global__ __launch_bounds__(256) void k_select(const unsigned short* __restrict__ sim,
                                                int grow0, int* __restrict__ cand_idx,
                                                float* __restrict__ cand_val) {
  __shared__ float tv[256 * 17];
  __shared__ int ti[256 * 17];
  const int t = threadIdx.x;
  const int s = t >> 5;    // split 0..7
  const int tt = t & 31;   // lane within split (half-wave aligned)
  const int row = blockIdx.x;
  const unsigned short* sr = sim + (size_t)row * NCPAD;

  // per-thread top-16 over its strided slice of the split
  int cnt = 0, minpos = 0;
  float minval = -3e38f;
  const int cstart = s * SPLITW, cend = cstart + SPLITW;
  for (int c = cstart + tt; c < cend; c += 32) {
    const float v = bf2f(sr[c]);
    if (cnt < CPS) {
      tv[t * 17 + cnt] = v;
      ti[t * 17 + cnt] = c;
      ++cnt;
      if (cnt == CPS) {
        float mv = tv[t * 17];
        int mp = 0;
#pragma unroll
        for (int q = 1; q < CPS; ++q) {
          const float w2 = tv[t * 17 + q];
          if (w2 < mv) { mv = w2; mp = q; }
        }
        minval = mv; minpos = mp;
      }
    } else if (v > minval) {
      tv[t * 17 + minpos] = v;
      ti[t * 17 + minpos] = c;
      float mv = tv[t * 17];
      int mp = 0;
#pragma unroll
      for (int q = 1; q < CPS; ++q) {
        const float w2 = tv[t * 17 + q];
        if (w2 < mv) { mv = w2; mp = q; }
      }
      minval = mv; minpos = mp;
    }
  }

  // merge 32 lists -> split top-16 via 16 rounds of half-wave argmax
  unsigned used = 0;
  const int gr = grow0 + row;
  for (int r = 0; r < CPS; ++r) {
    float bv = -3e38f;
    int bidx = 0x7fffffff, bslot = -1;
#pragma unroll
    for (int k = 0; k < CPS; ++k) {
      if (!((used >> k) & 1)) {
        const float v = tv[t * 17 + k];
        const int id = ti[t * 17 + k];
        if (v > bv || (v == bv && id < bidx)) { bv = v; bidx = id; bslot = k; }
      }
    }
    float cv = bv;
    int cid = bidx;
#pragma unroll
    for (int off = 1; off < 32; off <<= 1) {
      const float ov = __shfl_xor(cv, off, 32);
      const int oi = __shfl_xor(cid, off, 32);
      if (ov > cv || (ov == cv && oi < cid)) { cv = ov; cid = oi; }
    }
    if (bslot >= 0 && bv == cv && bidx == cid) used |= 1u << bslot;
    if (tt == 0) {
      cand_idx[(size_t)gr * NCAND + s * CPS + r] = cid;
      cand_val[(size_t)gr * NCAND + s * CPS + r] = cv;
    }
  }
}

// -------------------- phase 2: top-32 pre-select + exact f64 rescore + rank top-10 --------------------
__global__ __launch_bounds__(256) void k_phase2(const float* __restrict__ x,
                                                const double* __restrict__ rinv,
                                                const int* __restrict__ cand_idx,
                                                const float* __restrict__ cand_val,
                                                int* __restrict__ nb) {
  const int i = blockIdx.x;
  const int t = threadIdx.x;
  const int lane = t & 63;
  const int wave = t >> 6;
  __shared__ float cv[NCAND];
  __shared__ int cix[NCAND];
  __shared__ int sel[NSEL];
  __shared__ float xi[FEAT];
  __shared__ double dsv[NSEL];

  if (t < NCAND) {
    cv[t] = cand_val[(size_t)i * NCAND + t];
    cix[t] = cand_idx[(size_t)i * NCAND + t];
  }
  xi[t] = x[(size_t)i * FEAT + t];
  xi[t + 256] = x[(size_t)i * FEAT + t + 256];
  __syncthreads();

  if (t < NCAND) {
    const float v = cv[t];
    const int id = cix[t];
    int rk = 0;
    for (int j = 0; j < NCAND; ++j)
      rk += (cv[j] > v) || (cv[j] == v && cix[j] < id);
    if (rk < NSEL) sel[rk] = id;
  }
  __syncthreads();

  const double ri = rinv[i];
  const float4 v0 = *(const float4*)(xi + lane * 8);
  const float4 v1 = *(const float4*)(xi + lane * 8 + 4);
#pragma unroll
  for (int q = 0; q < 8; ++q) {
    const int c = wave * 8 + q;
    const int ci = sel[c];
    const float4* xr = (const float4*)(x + (size_t)ci * FEAT);
    const float4 u0 = xr[lane * 2];
    const float4 u1 = xr[lane * 2 + 1];
    double s = (double)u0.x * (double)v0.x + (double)u0.y * (double)v0.y +
               (double)u0.z * (double)v0.z + (double)u0.w * (double)v0.w +
               (double)u1.x * (double)v1.x + (double)u1.y * (double)v1.y +
               (double)u1.z * (double)v1.z + (double)u1.w * (double)v1.w;
#pragma unroll
    for (int off = 1; off < 64; off <<= 1) s += __shfl_xor(s, off);
    if (lane == 0) dsv[c] = s * ri * rinv[ci];
  }
  __syncthreads();

  if (t < NSEL) {
    const double v = dsv[t];
    const int id = sel[t];
    int rk = 0;
    for (int j = 0; j < NSEL; ++j)
      rk += (dsv[j] > v) || (dsv[j] == v && sel[j] < id);
    if (rk >= 1 && rk < KTOP) nb[(size_t)i * NNB + (rk - 1)] = id;
  }
}

// -------------------- CSR build helpers --------------------
__global__ void k_zero(int* __restrict__ p, int n) {
  const int i = blockIdx.x * blockDim.x + threadIdx.x;
  if (i < n) p[i] = 0;
}

__global__ void k_count(const int* __restrict__ dsts, int ne, int* __restrict__ cnt) {
  const int e = blockIdx.x * blockDim.x + threadIdx.x;
  if (e < ne) atomicAdd(&cnt[dsts[e]], 1);
}

__global__ void k_scan(const int* __restrict__ cnt, int n, int* __restrict__ off,
                       int* __restrict__ cur, float* __restrict__ dinv) {
  __shared__ int buf[1024];
  __shared__ int base_s;
  const int t = threadIdx.x;
  if (t == 0) base_s = 0;
  __syncthreads();
  for (int b0 = 0; b0 < n; b0 += 1024) {
    const int i = b0 + t;
    const int v = (i < n) ? cnt[i] : 0;
    buf[t] = v;
    __syncthreads();
    for (int o = 1; o < 1024; o <<= 1) {
      const int add = (t >= o) ? buf[t - o] : 0;
      __syncthreads();
      buf[t] += add;
      __syncthreads();
    }
    const int incl = buf[t];
    const int base = base_s;
    if (i < n) {
      const int excl = base + incl - v;
      off[i] = excl;
      cur[i] = excl;
      dinv[i] = rsqrtf((float)(v + 1));
    }
    __syncthreads();
    if (t == 1023) base_s = base + buf[1023];
    __syncthreads();
  }
  if (t == 0) off[n] = base_s;
}

__global__ void k_scatter_s(const int* __restrict__ src, const int* __restrict__ dst, int ne,
                            int* __restrict__ cur, int* __restrict__ csr) {
  const int e = blockIdx.x * blockDim.x + threadIdx.x;
  if (e < ne) {
    const int p = atomicAdd(&cur[dst[e]], 1);
    csr[p] = src[e];
  }
}

__global__ void k_scatter_t(const int* __restrict__ nb, int* __restrict__ cur,
                            int* __restrict__ csr) {
  const int e = blockIdx.x * blockDim.x + threadIdx.x;
  if (e < N_NODES * NNB) {
    const int i = e / NNB;
    const int v = nb[e];
    const int p = atomicAdd(&cur[v], 1);
    csr[p] = i;
  }
}

// -------------------- generic f32 GEMM: C[MxN] = A[MxK] @ B[KxN] --------------------
#define GBM 64
#define GBN 64
#define GBK 16
__global__ __launch_bounds__(256) void k_gemm(const float* __restrict__ A,
                                              const float* __restrict__ B,
                                              float* __restrict__ C, int M, int K, int N) {
  __shared__ float As[GBK][GBM + 4];
  __shared__ float Bs[GBK][GBN + 4];
  const int m0 = blockIdx.x * GBM, n0 = blockIdx.y * GBN;
  const int t = threadIdx.x;
  const int ty = t >> 4, tx = t & 15;
  float acc[4][4] = {};
  for (int k0 = 0; k0 < K; k0 += GBK) {
    {
      const int r = t >> 2, kq = (t & 3) * 4;
      const int gm = min(m0 + r, M - 1);
      const float4 v = *(const float4*)(A + (size_t)gm * K + k0 + kq);
      As[kq + 0][r] = v.x;
      As[kq + 1][r] = v.y;
      As[kq + 2][r] = v.z;
      As[kq + 3][r] = v.w;
      const int kk = t >> 4, nq = (t & 15) * 4;
      const float4 w = *(const float4*)(B + (size_t)(k0 + kk) * N + n0 + nq);
      *(float4*)&Bs[kk][nq] = w;
    }
    __syncthreads();
#pragma unroll
    for (int k = 0; k < GBK; ++k) {
      float a[4], b[4];
      *(float4*)&a[0] = *(const float4*)&As[k][ty * 4];
      *(float4*)&b[0] = *(const float4*)&Bs[k][tx * 4];
#pragma unroll
      for (int i = 0; i < 4; ++i)
#pragma unroll
        for (int j = 0; j < 4; ++j) acc[i][j] += a[i] * b[j];
    }
    __syncthreads();
  }
#pragma unroll
  for (int i = 0; i < 4; ++i) {
    const int gm = m0 + ty * 4 + i;
    if (gm < M) {
#pragma unroll
      for (int j = 0; j < 4; ++j) C[(size_t)gm * N + n0 + tx * 4 + j] = acc[i][j];
    }
  }
}

// -------------------- GCN aggregation --------------------
__global__ void k_agg(const float* __restrict__ h, const float* __restrict__ bias,
                      const float* __restrict__ dinv, const int* __restrict__ off,
                      const int* __restrict__ csr, float* __restrict__ out, int C,
                      int do_relu) {
  const int v = blockIdx.x;
  const int c = threadIdx.x;
  const float dv = dinv[v];
  float acc = h[(size_t)v * C + c] * dv;
  const int s0 = off[v], s1 = off[v + 1];
  for (int e = s0; e < s1; ++e) {
    const int s = csr[e];
    acc += h[(size_t)s * C + c] * dinv[s];
  }
  acc = acc * dv + bias[c];
  if (do_relu) acc = fmaxf(acc, 0.f);
  out[(size_t)v * C + c] = acc;
}

// -------------------- fusion + Student-t soft assignment --------------------
__global__ void k_fuse(const float* __restrict__ zs, const float* __restrict__ zt,
                       const float* __restrict__ fw, const float* __restrict__ cent,
                       float* __restrict__ out_z, float* __restrict__ out_q) {
  const int v = blockIdx.x;
  const int t = threadIdx.x;  // 128
  __shared__ float zsh[EMB];
  __shared__ float cs[NC][EMB];
  __shared__ float qv[NC];
  __shared__ float qs;
  for (int k = t; k < NC * EMB; k += 128) ((float*)cs)[k] = cent[k];
  const float beta = 1.f / (1.f + expf(-fw[0]));
  const float z = beta * zs[(size_t)v * EMB + t] + (1.f - beta) * zt[(size_t)v * EMB + t];
  out_z[(size_t)v * EMB + t] = z;
  zsh[t] = z;
  __syncthreads();
  if (t < NC) {
    float s = 0.f;
    for (int c = 0; c < EMB; ++c) {
      const float d = zsh[c] - cs[t][c];
      s += d * d;
    }
    qv[t] = 1.f / (1.f + s);
  }
  __syncthreads();
  if (t == 0) {
    float s = 0.f;
    for (int k = 0; k < NC; ++k) s += qv[k];
    qs = s;
  }
  __syncthreads();
  if (t < NC) out_q[(size_t)v * NC + t] = qv[t] / qs;
}

extern "C" void kernel_launch(void* const* d_in, const int* in_sizes, int n_in, void* d_out,
                              int out_size, void* d_ws, size_t ws_size, hipStream_t stream) {
  const float* x = (const float*)d_in[0];
  const int* ei = (const int*)d_in[1];
  const float* W_s1 = (const float*)d_in[2];
  const float* b_s1 = (const float*)d_in[3];
  const float* W_s2 = (const float*)d_in[4];
  const float* b_s2 = (const float*)d_in[5];
  const float* W_t1 = (const float*)d_in[6];
  const float* b_t1 = (const float*)d_in[7];
  const float* W_t2 = (const float*)d_in[8];
  const float* b_t2 = (const float*)d_in[9];
  const float* fw = (const float*)d_in[10];
  const float* cent = (const float*)d_in[11];
  float* out_z = (float*)d_out;
  float* out_q = out_z + (size_t)N_NODES * EMB;

  char* w = (char*)d_ws;
  size_t o = 0;
  auto alloc = [&](size_t bytes) -> void* {
    void* p = w + o;
    o += (bytes + 255) & ~(size_t)255;
    return p;
  };
  // xnb (sim GEMM input) -> h1_s after last sim stripe
  unsigned short* xnb = (unsigned short*)alloc((size_t)N_NODES * FEAT * 2);  // 10.24 MB
  float* h1_s = (float*)xnb;
  double* rinv = (double*)alloc((size_t)N_NODES * 8);
  // r1_s region holds cand_idx+cand_val until after phase2
  float* r1_s = (float*)alloc((size_t)N_NODES * HID * 4);  // 10.24 MB
  int* cand_idx = (int*)r1_s;                              // 5.12 MB
  float* cand_val = (float*)(r1_s + (size_t)N_NODES * NCAND);  // 5.12 MB
  // r1_t..h2_t region (30.7 MB) holds the 25.9 MB sim stripe until after selection
  float* r1_t = (float*)alloc((size_t)N_NODES * HID * 4);
  float* h1_t = (float*)alloc((size_t)N_NODES * HID * 4);
  float* h2_s = (float*)alloc((size_t)N_NODES * EMB * 4);
  float* h2_t = (float*)alloc((size_t)N_NODES * EMB * 4);
  unsigned short* simbuf = (unsigned short*)r1_t;  // STRIPE_ROWS*NCPAD*2 = 25.89 MB
  float* z_s = (float*)alloc((size_t)N_NODES * EMB * 4);
  float* z_t = (float*)alloc((size_t)N_NODES * EMB * 4);
  int* nb = (int*)alloc((size_t)N_NODES * NNB * 4);
  int* cnt_s = (int*)alloc((size_t)N_NODES * 4);
  int* off_s = (int*)alloc((size_t)(N_NODES + 1) * 4);
  int* cur_s = (int*)alloc((size_t)N_NODES * 4);
  float* dinv_s = (float*)alloc((size_t)N_NODES * 4);
  int* cnt_t = (int*)alloc((size_t)N_NODES * 4);
  int* off_t = (int*)alloc((size_t)(N_NODES + 1) * 4);
  int* cur_t = (int*)alloc((size_t)N_NODES * 4);
  float* dinv_t = (float*)alloc((size_t)N_NODES * 4);
  int* csr_s = (int*)alloc((size_t)NE_EDGES * 4);
  int* csr_t = (int*)alloc((size_t)N_NODES * NNB * 4);

  const int* e_src = ei;
  const int* e_dst = ei + NE_EDGES;

  // 1. norms -> bf16 normalized rows + f64 inv norms
  k_norms<<<N_NODES, 128, 0, stream>>>(x, xnb, rinv);
  // 2. structural degree counters (independent)
  k_zero<<<(N_NODES + 255) / 256, 256, 0, stream>>>(cnt_s, N_NODES);
  k_zero<<<(N_NODES + 255) / 256, 256, 0, stream>>>(cnt_t, N_NODES);
  k_count<<<(NE_EDGES + 255) / 256, 256, 0, stream>>>(e_dst, NE_EDGES, cnt_s);
  // 3. sim stripes: GEMM -> selection (stream-serialized reuse of simbuf)
  for (int s = 0; s < NSTRIPE; ++s) {
    const int row0 = s * STRIPE_ROWS;
    const int nrowt = min(10, 79 - s * 10);
    const int nrows = min(STRIPE_ROWS, N_NODES - row0);
    dim3 gg(79, nrowt);
    k_simgemm<<<gg, 256, 0, stream>>>(xnb, simbuf, row0);
    k_select<<<nrows, 256, 0, stream>>>(simbuf, row0, cand_idx, cand_val);
  }
  // 4. phase-2: top-32 pre-select + exact f64 rescore -> 9 neighbors
  k_phase2<<<N_NODES, 256, 0, stream>>>(x, rinv, cand_idx, cand_val, nb);
  // 5. topology degrees + scans + scatter
  k_count<<<(N_NODES * NNB + 255) / 256, 256, 0, stream>>>(nb, N_NODES * NNB, cnt_t);
  k_scan<<<1, 1024, 0, stream>>>(cnt_s, N_NODES, off_s, cur_s, dinv_s);
  k_scan<<<1, 1024, 0, stream>>>(cnt_t, N_NODES, off_t, cur_t, dinv_t);
  k_scatter_s<<<(NE_EDGES + 255) / 256, 256, 0, stream>>>(e_src, e_dst, NE_EDGES, cur_s, csr_s);
  k_scatter_t<<<(N_NODES * NNB + 255) / 256, 256, 0, stream>>>(nb, cur_t, csr_t);
  // 6. layer-1 GEMMs (h1_s aliases xnb: safe, sim stripes done)
  {
    dim3 g1((N_NODES + GBM - 1) / GBM, HID / GBN);
    k_gemm<<<g1, 256, 0, stream>>>(x, W_s1, h1_s, N_NODES, FEAT, HID);
    k_gemm<<<g1, 256, 0, stream>>>(x, W_t1, h1_t, N_NODES, FEAT, HID);
  }
  // 7. layer-1 aggregation + relu (r1_s overwrites cand arrays: safe, phase2 done)
  k_agg<<<N_NODES, HID, 0, stream>>>(h1_s, b_s1, dinv_s, off_s, csr_s, r1_s, HID, 1);
  k_agg<<<N_NODES, HID, 0, stream>>>(h1_t, b_t1, dinv_t, off_t, csr_t, r1_t, HID, 1);
  // 8. layer-2 GEMMs
  {
    dim3 g2((N_NODES + GBM - 1) / GBM, EMB / GBN);
    k_gemm<<<g2, 256, 0, stream>>>(r1_s, W_s2, h2_s, N_NODES, HID, EMB);
    k_gemm<<<g2, 256, 0, stream>>>(r1_t, W_t2, h2_t, N_NODES, HID, EMB);
  }
  // 9. layer-2 aggregation
  k_agg<<<N_NODES, EMB, 0, stream>>>(h2_s, b_s2, dinv_s, off_s, csr_s, z_s, EMB, 0);
  k_agg<<<N_NODES, EMB, 0, stream>>>(h2_t, b_t2, dinv_t, off_t, csr_t, z_t, EMB, 0);
  // 10. fusion + soft assignment
  k_fuse<<<N_NODES, 128, 0, stream>>>(z_s, z_t, fw, cent, out_z, out_q);
}

// Round 4
// 741.242 us; speedup vs baseline: 6.7117x; 1.9687x over previous
//
#include <hip/hip_runtime.h>
#include <math.h>

#define N_NODES 10000
#define FEAT 512
#define HID 256
#define EMB 128
#define NC 10
#define NE_EDGES 160000
#define KTOP 10
#define NNB 9

#define NSEL 32                // global top-32 candidates per row, f64-rescored
#define NCPAD 10112            // 79*128
#define STRIPE_ROWS 1280       // 10 tile-rows per stripe
#define NSTRIPE 8
#define NBIN 2048
#define EQCAP 1024

typedef __attribute__((ext_vector_type(8))) short short8;
typedef __attribute__((ext_vector_type(4))) float f32x4;

typedef const __attribute__((address_space(1))) unsigned int* gas1_t;
typedef __attribute__((address_space(3))) unsigned int* las3_t;

__device__ __forceinline__ void gload_lds16(const void* g, void* l) {
  __builtin_amdgcn_global_load_lds((gas1_t)g, (las3_t)l, 16, 0, 0);
}

__device__ __forceinline__ unsigned short f2bf(float f) {
  unsigned int u = __float_as_uint(f);
  u = (u + 0x7fffu + ((u >> 16) & 1u)) >> 16;
  return (unsigned short)u;
}
__device__ __forceinline__ float bf2f(unsigned short b) {
  return __uint_as_float(((unsigned int)b) << 16);
}
// order-preserving bf16 -> u16 key (monotone: bigger float -> bigger key)
__device__ __forceinline__ unsigned bfkey(unsigned u) {
  return (u & 0x8000u) ? (~u & 0xffffu) : (u | 0x8000u);
}

// -------------------- row norms -> bf16 normalized rows + f64 inv norms --------------------
__global__ void k_norms(const float* __restrict__ x, unsigned short* __restrict__ xnb,
                        double* __restrict__ rinv) {
  const int row = blockIdx.x;
  const int t = threadIdx.x;  // 128
  const float* xr = x + (size_t)row * FEAT;
  double s = 0.0;
  for (int k = t; k < FEAT; k += 128) { const double v = (double)xr[k]; s += v * v; }
  __shared__ double red[128];
  red[t] = s;
  __syncthreads();
  for (int o = 64; o > 0; o >>= 1) {
    if (t < o) red[t] += red[t + o];
    __syncthreads();
  }
  const double inv = 1.0 / fmax(sqrt(red[0]), 1e-12);
  const float finv = (float)inv;
  for (int k = t; k < FEAT; k += 128) xnb[(size_t)row * FEAT + k] = f2bf(xr[k] * finv);
  if (t == 0) rinv[row] = inv;
}

// -------------------- sim GEMM: stripe of C = Xn @ Xn^T (bf16 out) --------------------
__global__ __launch_bounds__(256) void k_simgemm(const unsigned short* __restrict__ xnb,
                                                 unsigned short* __restrict__ sim, int row0) {
  __shared__ __align__(16) char smem[34816];
  unsigned short* As = (unsigned short*)smem;            // [2][128*32]
  unsigned short* Bs = (unsigned short*)(smem + 16384);  // [2][128*32]
  unsigned short* Cs = (unsigned short*)smem;            // [128][136] (reused)

  const int t = threadIdx.x;
  const int lane = t & 63;
  const int w = t >> 6;
  const int lr = lane & 15;
  const int lk = lane >> 4;
  const int wr = (w >> 1) * 64, wc = (w & 1) * 64;
  const int btx = blockIdx.x, by = blockIdx.y;
  const int arow0 = row0 + by * 128;
  const int bcol0 = btx * 128;

  auto stage = [&](int b, int k0) {
#pragma unroll
    for (int it = 0; it < 2; ++it) {
      const int slot = it * 256 + w * 64 + lane;
      const int r = slot >> 2, q = slot & 3;
      {
        const int gr = min(arow0 + r, N_NODES - 1);
        gload_lds16(xnb + (size_t)gr * FEAT + k0 + q * 8,
                    As + b * 4096 + (it * 256 + w * 64) * 8);
      }
      {
        const int gr = min(bcol0 + r, N_NODES - 1);
        gload_lds16(xnb + (size_t)gr * FEAT + k0 + q * 8,
                    Bs + b * 4096 + (it * 256 + w * 64) * 8);
      }
    }
  };

  f32x4 acc[4][4];
#pragma unroll
  for (int m = 0; m < 4; ++m)
#pragma unroll
    for (int n = 0; n < 4; ++n) acc[m][n] = (f32x4){0.f, 0.f, 0.f, 0.f};

  stage(0, 0);
  __syncthreads();

  int cur = 0;
  const int NT = FEAT / 32;  // 16
  for (int kt = 0; kt < NT; ++kt) {
    if (kt + 1 < NT) stage(cur ^ 1, (kt + 1) * 32);
    const unsigned short* Ab = As + cur * 4096;
    const unsigned short* Bb = Bs + cur * 4096;
    short8 a[4], b[4];
#pragma unroll
    for (int m = 0; m < 4; ++m)
      a[m] = *(const short8*)(Ab + (wr + m * 16 + lr) * 32 + lk * 8);
#pragma unroll
    for (int n = 0; n < 4; ++n)
      b[n] = *(const short8*)(Bb + (wc + n * 16 + lr) * 32 + lk * 8);
#pragma unroll
    for (int m = 0; m < 4; ++m)
#pragma unroll
      for (int n = 0; n < 4; ++n)
        acc[m][n] = __builtin_amdgcn_mfma_f32_16x16x32_bf16(a[m], b[n], acc[m][n], 0, 0, 0);
    __syncthreads();
    cur ^= 1;
  }

  // epilogue: acc -> Cs (bf16) -> coalesced global store. C/D: col=lane&15, row=(lane>>4)*4+reg
#pragma unroll
  for (int m = 0; m < 4; ++m) {
    const int rb = wr + m * 16 + lk * 4;
#pragma unroll
    for (int n = 0; n < 4; ++n) {
      const int c = wc + n * 16 + lr;
#pragma unroll
      for (int q = 0; q < 4; ++q) Cs[(rb + q) * 136 + c] = f2bf(acc[m][n][q]);
    }
  }
  __syncthreads();
#pragma unroll
  for (int it = 0; it < 8; ++it) {
    const int slot = it * 256 + t;
    const int r = slot >> 4, q = slot & 15;
    const uint4 v = *(const uint4*)((const char*)Cs + r * 272 + q * 16);
    *(uint4*)(sim + (size_t)(by * 128 + r) * NCPAD + bcol0 + q * 8) = v;
  }
}

// -------------------- selection: histogram-based global top-32 per row --------------------
// Pass 1: 2048-bin LDS histogram of order-preserving keys (uint4 loads, 8 bf16 each).
// Suffix scan -> bin B holding the 32nd value. Pass 2: compact bin>B directly to output,
// bin==B to LDS list, exact-rank the list by (key desc, idx asc) for remaining slots.
__global__ __launch_bounds__(256) void k_select(const unsigned short* __restrict__ sim,
                                                int grow0, int* __restrict__ cand_idx) {
  __shared__ int hist[NBIN];
  __shared__ int buf[256];
  __shared__ unsigned eqp[EQCAP];
  __shared__ int Bsh, hiTotSh, hi_cnt, eq_cnt;

  const int t = threadIdx.x;
  const int row = blockIdx.x;
  const unsigned short* sr = sim + (size_t)row * NCPAD;
  int* outp = cand_idx + (size_t)(grow0 + row) * NSEL;

#pragma unroll
  for (int k = 0; k < NBIN / 256; ++k) hist[t + k * 256] = 0;
  if (t == 0) { hi_cnt = 0; eq_cnt = 0; }
  __syncthreads();

  // pass 1: histogram (10000 = 1250 uint4)
  for (int c8 = t; c8 < 1250; c8 += 256) {
    const uint4 v = *(const uint4*)(sr + c8 * 8);
    const unsigned uu[4] = {v.x, v.y, v.z, v.w};
#pragma unroll
    for (int j = 0; j < 4; ++j) {
      atomicAdd(&hist[bfkey(uu[j] & 0xffffu) >> 5], 1);
      atomicAdd(&hist[bfkey(uu[j] >> 16) >> 5], 1);
    }
  }
  __syncthreads();

  // suffix scan over 256 groups of 8 bins
  int sm = 0;
#pragma unroll
  for (int j = 0; j < 8; ++j) sm += hist[t * 8 + j];
  buf[t] = sm;
  __syncthreads();
  for (int o = 1; o < 256; o <<= 1) {
    const int v = (t + o < 256) ? buf[t + o] : 0;
    __syncthreads();
    buf[t] += v;
    __syncthreads();
  }
  // find bin B: cnt(bins > B) < NSEL <= cnt(bins >= B)
  {
    int cgt = (t + 1 < 256) ? buf[t + 1] : 0;
    for (int j = 7; j >= 0; --j) {
      const int h = hist[t * 8 + j];
      if (cgt < NSEL && cgt + h >= NSEL) { Bsh = t * 8 + j; hiTotSh = cgt; }
      cgt += h;
    }
  }
  __syncthreads();
  const int B = Bsh;

  // pass 2: compact
  for (int c8 = t; c8 < 1250; c8 += 256) {
    const uint4 v = *(const uint4*)(sr + c8 * 8);
    const unsigned uu[4] = {v.x, v.y, v.z, v.w};
#pragma unroll
    for (int j = 0; j < 8; ++j) {
      const unsigned raw = (j & 1) ? (uu[j >> 1] >> 16) : (uu[j >> 1] & 0xffffu);
      const unsigned key = bfkey(raw);
      const int b = (int)(key >> 5);
      const int col = c8 * 8 + j;
      if (b > B) {
        const int pos = atomicAdd(&hi_cnt, 1);
        outp[pos] = col;
      } else if (b == B) {
        const int pos = atomicAdd(&eq_cnt, 1);
        if (pos < EQCAP) eqp[pos] = (key << 16) | (16383u - (unsigned)col);
      }
    }
  }
  __syncthreads();

  // exact rank within bin B for the remaining slots
  const int hiTot = hiTotSh;
  const int need = NSEL - hiTot;
  const int L = min(eq_cnt, EQCAP);
  for (int e = t; e < L; e += 256) {
    const unsigned p = eqp[e];
    int rk = 0;
    for (int j = 0; j < L; ++j) rk += (eqp[j] > p);
    if (rk < need) outp[hiTot + rk] = 16383 - (int)(p & 0xffffu);
  }
}

// -------------------- phase 2: exact f64 rescore of 32 candidates + rank top-10 --------------------
__global__ __launch_bounds__(256) void k_phase2(const float* __restrict__ x,
                                                const double* __restrict__ rinv,
                                                const int* __restrict__ cand_idx,
                                                int* __restrict__ nb) {
  const int i = blockIdx.x;
  const int t = threadIdx.x;
  const int lane = t & 63;
  const int wave = t >> 6;
  __shared__ int sel[NSEL];
  __shared__ float xi[FEAT];
  __shared__ double dsv[NSEL];

  if (t < NSEL) sel[t] = cand_idx[(size_t)i * NSEL + t];
  xi[t] = x[(size_t)i * FEAT + t];
  xi[t + 256] = x[(size_t)i * FEAT + t + 256];
  __syncthreads();

  const double ri = rinv[i];
  const float4 v0 = *(const float4*)(xi + lane * 8);
  const float4 v1 = *(const float4*)(xi + lane * 8 + 4);
#pragma unroll
  for (int q = 0; q < 8; ++q) {
    const int c = wave * 8 + q;
    const int ci = sel[c];
    const float4* xr = (const float4*)(x + (size_t)ci * FEAT);
    const float4 u0 = xr[lane * 2];
    const float4 u1 = xr[lane * 2 + 1];
    double s = (double)u0.x * (double)v0.x + (double)u0.y * (double)v0.y +
               (double)u0.z * (double)v0.z + (double)u0.w * (double)v0.w +
               (double)u1.x * (double)v1.x + (double)u1.y * (double)v1.y +
               (double)u1.z * (double)v1.z + (double)u1.w * (double)v1.w;
#pragma unroll
    for (int off = 1; off < 64; off <<= 1) s += __shfl_xor(s, off);
    if (lane == 0) dsv[c] = s * ri * rinv[ci];
  }
  __syncthreads();

  if (t < NSEL) {
    const double v = dsv[t];
    const int id = sel[t];
    int rk = 0;
    for (int j = 0; j < NSEL; ++j)
      rk += (dsv[j] > v) || (dsv[j] == v && sel[j] < id);
    if (rk >= 1 && rk < KTOP) nb[(size_t)i * NNB + (rk - 1)] = id;
  }
}

// -------------------- CSR build helpers --------------------
__global__ void k_zero(int* __restrict__ p, int n) {
  const int i = blockIdx.x * blockDim.x + threadIdx.x;
  if (i < n) p[i] = 0;
}

__global__ void k_count(const int* __restrict__ dsts, int ne, int* __restrict__ cnt) {
  const int e = blockIdx.x * blockDim.x + threadIdx.x;
  if (e < ne) atomicAdd(&cnt[dsts[e]], 1);
}

__global__ void k_scan(const int* __restrict__ cnt, int n, int* __restrict__ off,
                       int* __restrict__ cur, float* __restrict__ dinv) {
  __shared__ int buf[1024];
  __shared__ int base_s;
  const int t = threadIdx.x;
  if (t == 0) base_s = 0;
  __syncthreads();
  for (int b0 = 0; b0 < n; b0 += 1024) {
    const int i = b0 + t;
    const int v = (i < n) ? cnt[i] : 0;
    buf[t] = v;
    __syncthreads();
    for (int o = 1; o < 1024; o <<= 1) {
      const int add = (t >= o) ? buf[t - o] : 0;
      __syncthreads();
      buf[t] += add;
      __syncthreads();
    }
    const int incl = buf[t];
    const int base = base_s;
    if (i < n) {
      const int excl = base + incl - v;
      off[i] = excl;
      cur[i] = excl;
      dinv[i] = rsqrtf((float)(v + 1));
    }
    __syncthreads();
    if (t == 1023) base_s = base + buf[1023];
    __syncthreads();
  }
  if (t == 0) off[n] = base_s;
}

__global__ void k_scatter_s(const int* __restrict__ src, const int* __restrict__ dst, int ne,
                            int* __restrict__ cur, int* __restrict__ csr) {
  const int e = blockIdx.x * blockDim.x + threadIdx.x;
  if (e < ne) {
    const int p = atomicAdd(&cur[dst[e]], 1);
    csr[p] = src[e];
  }
}

__global__ void k_scatter_t(const int* __restrict__ nb, int* __restrict__ cur,
                            int* __restrict__ csr) {
  const int e = blockIdx.x * blockDim.x + threadIdx.x;
  if (e < N_NODES * NNB) {
    const int i = e / NNB;
    const int v = nb[e];
    const int p = atomicAdd(&cur[v], 1);
    csr[p] = i;
  }
}

// -------------------- generic f32 GEMM: C[MxN] = A[MxK] @ B[KxN] --------------------
#define GBM 64
#define GBN 64
#define GBK 16
__global__ __launch_bounds__(256) void k_gemm(const float* __restrict__ A,
                                              const float* __restrict__ B,
                                              float* __restrict__ C, int M, int K, int N) {
  __shared__ float As[GBK][GBM + 4];
  __shared__ float Bs[GBK][GBN + 4];
  const int m0 = blockIdx.x * GBM, n0 = blockIdx.y * GBN;
  const int t = threadIdx.x;
  const int ty = t >> 4, tx = t & 15;
  float acc[4][4] = {};
  for (int k0 = 0; k0 < K; k0 += GBK) {
    {
      const int r = t >> 2, kq = (t & 3) * 4;
      const int gm = min(m0 + r, M - 1);
      const float4 v = *(const float4*)(A + (size_t)gm * K + k0 + kq);
      As[kq + 0][r] = v.x;
      As[kq + 1][r] = v.y;
      As[kq + 2][r] = v.z;
      As[kq + 3][r] = v.w;
      const int kk = t >> 4, nq = (t & 15) * 4;
      const float4 w = *(const float4*)(B + (size_t)(k0 + kk) * N + n0 + nq);
      *(float4*)&Bs[kk][nq] = w;
    }
    __syncthreads();
#pragma unroll
    for (int k = 0; k < GBK; ++k) {
      float a[4], b[4];
      *(float4*)&a[0] = *(const float4*)&As[k][ty * 4];
      *(float4*)&b[0] = *(const float4*)&Bs[k][tx * 4];
#pragma unroll
      for (int i = 0; i < 4; ++i)
#pragma unroll
        for (int j = 0; j < 4; ++j) acc[i][j] += a[i] * b[j];
    }
    __syncthreads();
  }
#pragma unroll
  for (int i = 0; i < 4; ++i) {
    const int gm = m0 + ty * 4 + i;
    if (gm < M) {
#pragma unroll
      for (int j = 0; j < 4; ++j) C[(size_t)gm * N + n0 + tx * 4 + j] = acc[i][j];
    }
  }
}

// -------------------- GCN aggregation --------------------
__global__ void k_agg(const float* __restrict__ h, const float* __restrict__ bias,
                      const float* __restrict__ dinv, const int* __restrict__ off,
                      const int* __restrict__ csr, float* __restrict__ out, int C,
                      int do_relu) {
  const int v = blockIdx.x;
  const int c = threadIdx.x;
  const float dv = dinv[v];
  float acc = h[(size_t)v * C + c] * dv;
  const int s0 = off[v], s1 = off[v + 1];
  for (int e = s0; e < s1; ++e) {
    const int s = csr[e];
    acc += h[(size_t)s * C + c] * dinv[s];
  }
  acc = acc * dv + bias[c];
  if (do_relu) acc = fmaxf(acc, 0.f);
  out[(size_t)v * C + c] = acc;
}

// -------------------- fusion + Student-t soft assignment --------------------
__global__ void k_fuse(const float* __restrict__ zs, const float* __restrict__ zt,
                       const float* __restrict__ fw, const float* __restrict__ cent,
                       float* __restrict__ out_z, float* __restrict__ out_q) {
  const int v = blockIdx.x;
  const int t = threadIdx.x;  // 128
  __shared__ float zsh[EMB];
  __shared__ float cs[NC][EMB];
  __shared__ float qv[NC];
  __shared__ float qs;
  for (int k = t; k < NC * EMB; k += 128) ((float*)cs)[k] = cent[k];
  const float beta = 1.f / (1.f + expf(-fw[0]));
  const float z = beta * zs[(size_t)v * EMB + t] + (1.f - beta) * zt[(size_t)v * EMB + t];
  out_z[(size_t)v * EMB + t] = z;
  zsh[t] = z;
  __syncthreads();
  if (t < NC) {
    float s = 0.f;
    for (int c = 0; c < EMB; ++c) {
      const float d = zsh[c] - cs[t][c];
      s += d * d;
    }
    qv[t] = 1.f / (1.f + s);
  }
  __syncthreads();
  if (t == 0) {
    float s = 0.f;
    for (int k = 0; k < NC; ++k) s += qv[k];
    qs = s;
  }
  __syncthreads();
  if (t < NC) out_q[(size_t)v * NC + t] = qv[t] / qs;
}

extern "C" void kernel_launch(void* const* d_in, const int* in_sizes, int n_in, void* d_out,
                              int out_size, void* d_ws, size_t ws_size, hipStream_t stream) {
  const float* x = (const float*)d_in[0];
  const int* ei = (const int*)d_in[1];
  const float* W_s1 = (const float*)d_in[2];
  const float* b_s1 = (const float*)d_in[3];
  const float* W_s2 = (const float*)d_in[4];
  const float* b_s2 = (const float*)d_in[5];
  const float* W_t1 = (const float*)d_in[6];
  const float* b_t1 = (const float*)d_in[7];
  const float* W_t2 = (const float*)d_in[8];
  const float* b_t2 = (const float*)d_in[9];
  const float* fw = (const float*)d_in[10];
  const float* cent = (const float*)d_in[11];
  float* out_z = (float*)d_out;
  float* out_q = out_z + (size_t)N_NODES * EMB;

  char* w = (char*)d_ws;
  size_t o = 0;
  auto alloc = [&](size_t bytes) -> void* {
    void* p = w + o;
    o += (bytes + 255) & ~(size_t)255;
    return p;
  };
  // xnb (sim GEMM input) -> h1_s after last sim stripe
  unsigned short* xnb = (unsigned short*)alloc((size_t)N_NODES * FEAT * 2);  // 10.24 MB
  float* h1_s = (float*)xnb;
  double* rinv = (double*)alloc((size_t)N_NODES * 8);
  // r1_s region holds cand_idx until after phase2
  float* r1_s = (float*)alloc((size_t)N_NODES * HID * 4);  // 10.24 MB
  int* cand_idx = (int*)r1_s;                              // 10000*32*4 = 1.28 MB
  // r1_t..h2_t region (30.7 MB) holds the 25.9 MB sim stripe until after selection
  float* r1_t = (float*)alloc((size_t)N_NODES * HID * 4);
  float* h1_t = (float*)alloc((size_t)N_NODES * HID * 4);
  float* h2_s = (float*)alloc((size_t)N_NODES * EMB * 4);
  float* h2_t = (float*)alloc((size_t)N_NODES * EMB * 4);
  unsigned short* simbuf = (unsigned short*)r1_t;  // STRIPE_ROWS*NCPAD*2 = 25.89 MB
  float* z_s = (float*)alloc((size_t)N_NODES * EMB * 4);
  float* z_t = (float*)alloc((size_t)N_NODES * EMB * 4);
  int* nb = (int*)alloc((size_t)N_NODES * NNB * 4);
  int* cnt_s = (int*)alloc((size_t)N_NODES * 4);
  int* off_s = (int*)alloc((size_t)(N_NODES + 1) * 4);
  int* cur_s = (int*)alloc((size_t)N_NODES * 4);
  float* dinv_s = (float*)alloc((size_t)N_NODES * 4);
  int* cnt_t = (int*)alloc((size_t)N_NODES * 4);
  int* off_t = (int*)alloc((size_t)(N_NODES + 1) * 4);
  int* cur_t = (int*)alloc((size_t)N_NODES * 4);
  float* dinv_t = (float*)alloc((size_t)N_NODES * 4);
  int* csr_s = (int*)alloc((size_t)NE_EDGES * 4);
  int* csr_t = (int*)alloc((size_t)N_NODES * NNB * 4);

  const int* e_src = ei;
  const int* e_dst = ei + NE_EDGES;

  // 1. norms -> bf16 normalized rows + f64 inv norms
  k_norms<<<N_NODES, 128, 0, stream>>>(x, xnb, rinv);
  // 2. structural degree counters (independent)
  k_zero<<<(N_NODES + 255) / 256, 256, 0, stream>>>(cnt_s, N_NODES);
  k_zero<<<(N_NODES + 255) / 256, 256, 0, stream>>>(cnt_t, N_NODES);
  k_count<<<(NE_EDGES + 255) / 256, 256, 0, stream>>>(e_dst, NE_EDGES, cnt_s);
  // 3. sim stripes: GEMM -> histogram top-32 selection
  for (int s = 0; s < NSTRIPE; ++s) {
    const int row0 = s * STRIPE_ROWS;
    const int nrowt = min(10, 79 - s * 10);
    const int nrows = min(STRIPE_ROWS, N_NODES - row0);
    dim3 gg(79, nrowt);
    k_simgemm<<<gg, 256, 0, stream>>>(xnb, simbuf, row0);
    k_select<<<nrows, 256, 0, stream>>>(simbuf, row0, cand_idx);
  }
  // 4. phase-2: exact f64 rescore of 32 candidates -> 9 neighbors
  k_phase2<<<N_NODES, 256, 0, stream>>>(x, rinv, cand_idx, nb);
  // 5. topology degrees + scans + scatter
  k_count<<<(N_NODES * NNB + 255) / 256, 256, 0, stream>>>(nb, N_NODES * NNB, cnt_t);
  k_scan<<<1, 1024, 0, stream>>>(cnt_s, N_NODES, off_s, cur_s, dinv_s);
  k_scan<<<1, 1024, 0, stream>>>(cnt_t, N_NODES, off_t, cur_t, dinv_t);
  k_scatter_s<<<(NE_EDGES + 255) / 256, 256, 0, stream>>>(e_src, e_dst, NE_EDGES, cur_s, csr_s);
  k_scatter_t<<<(N_NODES * NNB + 255) / 256, 256, 0, stream>>>(nb, cur_t, csr_t);
  // 6. layer-1 GEMMs (h1_s aliases xnb: safe, sim stripes done)
  {
    dim3 g1((N_NODES + GBM - 1) / GBM, HID / GBN);
    k_gemm<<<g1, 256, 0, stream>>>(x, W_s1, h1_s, N_NODES, FEAT, HID);
    k_gemm<<<g1, 256, 0, stream>>>(x, W_t1, h1_t, N_NODES, FEAT, HID);
  }
  // 7. layer-1 aggregation + relu (r1_s overwrites cand_idx: safe, phase2 done)
  k_agg<<<N_NODES, HID, 0, stream>>>(h1_s, b_s1, dinv_s, off_s, csr_s, r1_s, HID, 1);
  k_agg<<<N_NODES, HID, 0, stream>>>(h1_t, b_t1, dinv_t, off_t, csr_t, r1_t, HID, 1);
  // 8. layer-2 GEMMs
  {
    dim3 g2((N_NODES + GBM - 1) / GBM, EMB / GBN);
    k_gemm<<<g2, 256, 0, stream>>>(r1_s, W_s2, h2_s, N_NODES, HID, EMB);
    k_gemm<<<g2, 256, 0, stream>>>(r1_t, W_t2, h2_t, N_NODES, HID, EMB);
  }
  // 9. layer-2 aggregation
  k_agg<<<N_NODES, EMB, 0, stream>>>(h2_s, b_s2, dinv_s, off_s, csr_s, z_s, EMB, 0);
  k_agg<<<N_NODES, EMB, 0, stream>>>(h2_t, b_t2, dinv_t, off_t, csr_t, z_t, EMB, 0);
  // 10. fusion + soft assignment
  k_fuse<<<N_NODES, 128, 0, stream>>>(z_s, z_t, fw, cent, out_z, out_q);
}

// Round 5
// 662.860 us; speedup vs baseline: 7.5053x; 1.1182x over previous
//
#include <hip/hip_runtime.h>
#include <math.h>

#define N_NODES 10000
#define FEAT 512
#define HID 256
#define EMB 128
#define NC 10
#define NE_EDGES 160000
#define KTOP 10
#define NNB 9

#define CAP 128          // per-row candidate buffer capacity
#define NSEL 16          // candidates f64-rescored
#define TAU 0.11f        // store threshold (sims ~ N(0,0.0442), s10 ~ 0.19)
#define SAFE_VAL 0.12f   // need >=10 stored above this, else fallback

typedef __attribute__((ext_vector_type(8))) short short8;
typedef __attribute__((ext_vector_type(4))) float f32x4;

typedef const __attribute__((address_space(1))) unsigned int* gas1_t;
typedef __attribute__((address_space(3))) unsigned int* las3_t;

__device__ __forceinline__ void gload_lds16(const void* g, void* l) {
  __builtin_amdgcn_global_load_lds((gas1_t)g, (las3_t)l, 16, 0, 0);
}

__device__ __forceinline__ unsigned short f2h(float f) {
  _Float16 h = (_Float16)f;
  return *(unsigned short*)&h;
}
__device__ __forceinline__ float h2f(unsigned short u) {
  _Float16 h = *(_Float16*)&u;
  return (float)h;
}

// -------------------- row norms -> f16 normalized rows + f64 inv norms --------------------
__global__ void k_norms(const float* __restrict__ x, unsigned short* __restrict__ xnf,
                        double* __restrict__ rinv) {
  const int row = blockIdx.x;
  const int t = threadIdx.x;  // 128
  const float* xr = x + (size_t)row * FEAT;
  double s = 0.0;
  for (int k = t; k < FEAT; k += 128) { const double v = (double)xr[k]; s += v * v; }
  __shared__ double red[128];
  red[t] = s;
  __syncthreads();
  for (int o = 64; o > 0; o >>= 1) {
    if (t < o) red[t] += red[t + o];
    __syncthreads();
  }
  const double inv = 1.0 / fmax(sqrt(red[0]), 1e-12);
  const float finv = (float)inv;
  for (int k = t; k < FEAT; k += 128) xnf[(size_t)row * FEAT + k] = f2h(xr[k] * finv);
  if (t == 0) rinv[row] = inv;
}

// -------------------- sim GEMM + in-register threshold filter (no sim matrix) --------------------
// grid (79, 79): 128x128 tile of Xn @ Xn^T in f16 MFMA; epilogue pushes values > TAU into
// per-row global candidate buffers (packed f16key<<16 | col) via atomic counters.
__global__ __launch_bounds__(256) void k_simgemm(const unsigned short* __restrict__ xnf,
                                                 unsigned int* __restrict__ cap_buf,
                                                 int* __restrict__ cnt_row) {
  __shared__ __align__(16) unsigned short As[2][128 * 32];
  __shared__ __align__(16) unsigned short Bs[2][128 * 32];

  const int t = threadIdx.x;
  const int lane = t & 63;
  const int w = t >> 6;
  const int lr = lane & 15;
  const int lk = lane >> 4;
  const int wr = (w >> 1) * 64, wc = (w & 1) * 64;
  const int arow0 = blockIdx.y * 128;
  const int bcol0 = blockIdx.x * 128;

  auto stage = [&](int b, int k0) {
#pragma unroll
    for (int it = 0; it < 2; ++it) {
      const int slot = it * 256 + w * 64 + lane;
      const int r = slot >> 2, q = slot & 3;
      {
        const int gr = min(arow0 + r, N_NODES - 1);
        gload_lds16(xnf + (size_t)gr * FEAT + k0 + q * 8, &As[b][(it * 256 + w * 64) * 8]);
      }
      {
        const int gr = min(bcol0 + r, N_NODES - 1);
        gload_lds16(xnf + (size_t)gr * FEAT + k0 + q * 8, &Bs[b][(it * 256 + w * 64) * 8]);
      }
    }
  };

  f32x4 acc[4][4];
#pragma unroll
  for (int m = 0; m < 4; ++m)
#pragma unroll
    for (int n = 0; n < 4; ++n) acc[m][n] = (f32x4){0.f, 0.f, 0.f, 0.f};

  stage(0, 0);
  __syncthreads();

  int cur = 0;
  const int NT = FEAT / 32;  // 16
  for (int kt = 0; kt < NT; ++kt) {
    if (kt + 1 < NT) stage(cur ^ 1, (kt + 1) * 32);
    const unsigned short* Ab = As[cur];
    const unsigned short* Bb = Bs[cur];
    short8 a[4], b[4];
#pragma unroll
    for (int m = 0; m < 4; ++m)
      a[m] = *(const short8*)(Ab + (wr + m * 16 + lr) * 32 + lk * 8);
#pragma unroll
    for (int n = 0; n < 4; ++n)
      b[n] = *(const short8*)(Bb + (wc + n * 16 + lr) * 32 + lk * 8);
#pragma unroll
    for (int m = 0; m < 4; ++m)
#pragma unroll
      for (int n = 0; n < 4; ++n)
        acc[m][n] = __builtin_amdgcn_mfma_f32_16x16x32_f16(a[m], b[n], acc[m][n], 0, 0, 0);
    __syncthreads();
    cur ^= 1;
  }

  // filter epilogue. C/D layout: col = lane&15, row = (lane>>4)*4 + reg
#pragma unroll
  for (int m = 0; m < 4; ++m) {
    const int rb = arow0 + wr + m * 16 + lk * 4;
#pragma unroll
    for (int n = 0; n < 4; ++n) {
      const int gc = bcol0 + wc + n * 16 + lr;
      if (gc < N_NODES) {
#pragma unroll
        for (int q = 0; q < 4; ++q) {
          const float v = acc[m][n][q];
          const int gr = rb + q;
          if (v > TAU && gr < N_NODES) {
            const int pos = atomicAdd(&cnt_row[gr], 1);
            if (pos < CAP)
              cap_buf[(size_t)gr * CAP + pos] = ((unsigned)f2h(v) << 16) | (unsigned)gc;
          }
        }
      }
    }
  }
}

// -------------------- fused select + exact f64 rescore -> 9 neighbors (set semantics) --------------------
__global__ __launch_bounds__(256) void k_knn(const float* __restrict__ x,
                                             const double* __restrict__ rinv,
                                             const unsigned int* __restrict__ cap_buf,
                                             const int* __restrict__ cnt_row,
                                             int* __restrict__ nb, int* __restrict__ flags) {
  const int i = blockIdx.x;
  const int t = threadIdx.x;
  const int lane = t & 63;
  const int wave = t >> 6;
  __shared__ unsigned pp[CAP];
  __shared__ int sel[NSEL];
  __shared__ float xi[FEAT];
  __shared__ double dsv[NSEL];
  __shared__ int safe_cnt;

  const int cnt = cnt_row[i];
  if (cnt > CAP || cnt < NSEL) {
    if (t == 0) flags[i] = 1;
    return;
  }
  if (t == 0) { flags[i] = 0; safe_cnt = 0; }
  const int L = cnt;
  if (t < L) pp[t] = cap_buf[(size_t)i * CAP + t];
  xi[t] = x[(size_t)i * FEAT + t];
  xi[t + 256] = x[(size_t)i * FEAT + t + 256];
  __syncthreads();

  // rank stored candidates by packed u32 desc (f16 val desc; distinct cols -> strict)
  if (t < L) {
    const unsigned p = pp[t];
    if (h2f((unsigned short)(p >> 16)) >= SAFE_VAL) atomicAdd(&safe_cnt, 1);
    int rk = 0;
    for (int j = 0; j < L; ++j) rk += (pp[j] > p);
    if (rk < NSEL) sel[rk] = (int)(p & 0xffffu);
  }
  __syncthreads();
  if (safe_cnt < KTOP) {
    if (t == 0) flags[i] = 1;
    return;
  }

  // exact f64 rescore of 16 candidates (wave per 4)
  const double ri = rinv[i];
  const float4 v0 = *(const float4*)(xi + lane * 8);
  const float4 v1 = *(const float4*)(xi + lane * 8 + 4);
#pragma unroll
  for (int q = 0; q < 4; ++q) {
    const int c = wave * 4 + q;
    const int ci = sel[c];
    const float4* xr = (const float4*)(x + (size_t)ci * FEAT);
    const float4 u0 = xr[lane * 2];
    const float4 u1 = xr[lane * 2 + 1];
    double s = (double)u0.x * (double)v0.x + (double)u0.y * (double)v0.y +
               (double)u0.z * (double)v0.z + (double)u0.w * (double)v0.w +
               (double)u1.x * (double)v1.x + (double)u1.y * (double)v1.y +
               (double)u1.z * (double)v1.z + (double)u1.w * (double)v1.w;
#pragma unroll
    for (int off = 1; off < 64; off <<= 1) s += __shfl_xor(s, off);
    if (lane == 0) dsv[c] = s * ri * rinv[ci];
  }
  __syncthreads();

  if (t < NSEL) {
    const double v = dsv[t];
    const int id = sel[t];
    int rk = 0;
    for (int j = 0; j < NSEL; ++j)
      rk += (dsv[j] > v) || (dsv[j] == v && sel[j] < id);
    if (rk >= 1 && rk < KTOP) nb[(size_t)i * NNB + (rk - 1)] = id;
  }
}

// -------------------- fallback: exact full scan for flagged rows (expected: none) --------------------
__global__ __launch_bounds__(256) void k_fallback(const float* __restrict__ x,
                                                  const double* __restrict__ rinv,
                                                  const int* __restrict__ flags,
                                                  int* __restrict__ nb) {
  const int i = blockIdx.x;
  if (!flags[i]) return;
  const int t = threadIdx.x;
  __shared__ float xi[FEAT];
  __shared__ double cval[256];
  __shared__ double bestv[NNB];
  __shared__ int besti[NNB];
  for (int k = t; k < FEAT; k += 256) xi[k] = x[(size_t)i * FEAT + k];
  if (t < NNB) { bestv[t] = -1e300; besti[t] = 0x7fffffff; }
  __syncthreads();
  const double ri = rinv[i];
  for (int c0 = 0; c0 < N_NODES; c0 += 256) {
    const int c = c0 + t;
    double s = -1e300;
    if (c < N_NODES && c != i) {
      s = 0.0;
      for (int k = 0; k < FEAT; ++k) s += (double)xi[k] * (double)x[(size_t)c * FEAT + k];
      s *= ri * rinv[c];
    }
    cval[t] = s;
    __syncthreads();
    if (t == 0) {
      for (int j = 0; j < 256; ++j) {
        const int c2 = c0 + j;
        const double v = cval[j];
        if (v == -1e300) continue;
        // insert into sorted top-9 (val desc, idx asc)
        int pos = NNB;
        for (int q = 0; q < NNB; ++q) {
          if (v > bestv[q] || (v == bestv[q] && c2 < besti[q])) { pos = q; break; }
        }
        if (pos < NNB) {
          for (int q = NNB - 1; q > pos; --q) { bestv[q] = bestv[q - 1]; besti[q] = besti[q - 1]; }
          bestv[pos] = v; besti[pos] = c2;
        }
      }
    }
    __syncthreads();
  }
  if (t < NNB) nb[(size_t)i * NNB + t] = besti[t];
}

// -------------------- CSR build helpers --------------------
__global__ void k_zero(int* __restrict__ p, int n) {
  const int i = blockIdx.x * blockDim.x + threadIdx.x;
  if (i < n) p[i] = 0;
}

__global__ void k_count(const int* __restrict__ dsts, int ne, int* __restrict__ cnt) {
  const int e = blockIdx.x * blockDim.x + threadIdx.x;
  if (e < ne) atomicAdd(&cnt[dsts[e]], 1);
}

__global__ void k_scan(const int* __restrict__ cnt, int n, int* __restrict__ off,
                       int* __restrict__ cur, float* __restrict__ dinv) {
  __shared__ int buf[1024];
  __shared__ int base_s;
  const int t = threadIdx.x;
  if (t == 0) base_s = 0;
  __syncthreads();
  for (int b0 = 0; b0 < n; b0 += 1024) {
    const int i = b0 + t;
    const int v = (i < n) ? cnt[i] : 0;
    buf[t] = v;
    __syncthreads();
    for (int o = 1; o < 1024; o <<= 1) {
      const int add = (t >= o) ? buf[t - o] : 0;
      __syncthreads();
      buf[t] += add;
      __syncthreads();
    }
    const int incl = buf[t];
    const int base = base_s;
    if (i < n) {
      const int excl = base + incl - v;
      off[i] = excl;
      cur[i] = excl;
      dinv[i] = rsqrtf((float)(v + 1));
    }
    __syncthreads();
    if (t == 1023) base_s = base + buf[1023];
    __syncthreads();
  }
  if (t == 0) off[n] = base_s;
}

__global__ void k_scatter_s(const int* __restrict__ src, const int* __restrict__ dst, int ne,
                            int* __restrict__ cur, int* __restrict__ csr) {
  const int e = blockIdx.x * blockDim.x + threadIdx.x;
  if (e < ne) {
    const int p = atomicAdd(&cur[dst[e]], 1);
    csr[p] = src[e];
  }
}

__global__ void k_scatter_t(const int* __restrict__ nb, int* __restrict__ cur,
                            int* __restrict__ csr) {
  const int e = blockIdx.x * blockDim.x + threadIdx.x;
  if (e < N_NODES * NNB) {
    const int i = e / NNB;
    const int v = nb[e];
    const int p = atomicAdd(&cur[v], 1);
    csr[p] = i;
  }
}

// -------------------- generic f32 GEMM: C[MxN] = A[MxK] @ B[KxN] --------------------
#define GBM 64
#define GBN 64
#define GBK 16
__global__ __launch_bounds__(256) void k_gemm(const float* __restrict__ A,
                                              const float* __restrict__ B,
                                              float* __restrict__ C, int M, int K, int N) {
  __shared__ float As[GBK][GBM + 4];
  __shared__ float Bs[GBK][GBN + 4];
  const int m0 = blockIdx.x * GBM, n0 = blockIdx.y * GBN;
  const int t = threadIdx.x;
  const int ty = t >> 4, tx = t & 15;
  float acc[4][4] = {};
  for (int k0 = 0; k0 < K; k0 += GBK) {
    {
      const int r = t >> 2, kq = (t & 3) * 4;
      const int gm = min(m0 + r, M - 1);
      const float4 v = *(const float4*)(A + (size_t)gm * K + k0 + kq);
      As[kq + 0][r] = v.x;
      As[kq + 1][r] = v.y;
      As[kq + 2][r] = v.z;
      As[kq + 3][r] = v.w;
      const int kk = t >> 4, nq = (t & 15) * 4;
      const float4 w = *(const float4*)(B + (size_t)(k0 + kk) * N + n0 + nq);
      *(float4*)&Bs[kk][nq] = w;
    }
    __syncthreads();
#pragma unroll
    for (int k = 0; k < GBK; ++k) {
      float a[4], b[4];
      *(float4*)&a[0] = *(const float4*)&As[k][ty * 4];
      *(float4*)&b[0] = *(const float4*)&Bs[k][tx * 4];
#pragma unroll
      for (int i = 0; i < 4; ++i)
#pragma unroll
        for (int j = 0; j < 4; ++j) acc[i][j] += a[i] * b[j];
    }
    __syncthreads();
  }
#pragma unroll
  for (int i = 0; i < 4; ++i) {
    const int gm = m0 + ty * 4 + i;
    if (gm < M) {
#pragma unroll
      for (int j = 0; j < 4; ++j) C[(size_t)gm * N + n0 + tx * 4 + j] = acc[i][j];
    }
  }
}

// -------------------- GCN aggregation --------------------
__global__ void k_agg(const float* __restrict__ h, const float* __restrict__ bias,
                      const float* __restrict__ dinv, const int* __restrict__ off,
                      const int* __restrict__ csr, float* __restrict__ out, int C,
                      int do_relu) {
  const int v = blockIdx.x;
  const int c = threadIdx.x;
  const float dv = dinv[v];
  float acc = h[(size_t)v * C + c] * dv;
  const int s0 = off[v], s1 = off[v + 1];
  for (int e = s0; e < s1; ++e) {
    const int s = csr[e];
    acc += h[(size_t)s * C + c] * dinv[s];
  }
  acc = acc * dv + bias[c];
  if (do_relu) acc = fmaxf(acc, 0.f);
  out[(size_t)v * C + c] = acc;
}

// -------------------- fusion + Student-t soft assignment --------------------
__global__ void k_fuse(const float* __restrict__ zs, const float* __restrict__ zt,
                       const float* __restrict__ fw, const float* __restrict__ cent,
                       float* __restrict__ out_z, float* __restrict__ out_q) {
  const int v = blockIdx.x;
  const int t = threadIdx.x;  // 128
  __shared__ float zsh[EMB];
  __shared__ float cs[NC][EMB];
  __shared__ float qv[NC];
  __shared__ float qs;
  for (int k = t; k < NC * EMB; k += 128) ((float*)cs)[k] = cent[k];
  const float beta = 1.f / (1.f + expf(-fw[0]));
  const float z = beta * zs[(size_t)v * EMB + t] + (1.f - beta) * zt[(size_t)v * EMB + t];
  out_z[(size_t)v * EMB + t] = z;
  zsh[t] = z;
  __syncthreads();
  if (t < NC) {
    float s = 0.f;
    for (int c = 0; c < EMB; ++c) {
      const float d = zsh[c] - cs[t][c];
      s += d * d;
    }
    qv[t] = 1.f / (1.f + s);
  }
  __syncthreads();
  if (t == 0) {
    float s = 0.f;
    for (int k = 0; k < NC; ++k) s += qv[k];
    qs = s;
  }
  __syncthreads();
  if (t < NC) out_q[(size_t)v * NC + t] = qv[t] / qs;
}

extern "C" void kernel_launch(void* const* d_in, const int* in_sizes, int n_in, void* d_out,
                              int out_size, void* d_ws, size_t ws_size, hipStream_t stream) {
  const float* x = (const float*)d_in[0];
  const int* ei = (const int*)d_in[1];
  const float* W_s1 = (const float*)d_in[2];
  const float* b_s1 = (const float*)d_in[3];
  const float* W_s2 = (const float*)d_in[4];
  const float* b_s2 = (const float*)d_in[5];
  const float* W_t1 = (const float*)d_in[6];
  const float* b_t1 = (const float*)d_in[7];
  const float* W_t2 = (const float*)d_in[8];
  const float* b_t2 = (const float*)d_in[9];
  const float* fw = (const float*)d_in[10];
  const float* cent = (const float*)d_in[11];
  float* out_z = (float*)d_out;
  float* out_q = out_z + (size_t)N_NODES * EMB;

  char* w = (char*)d_ws;
  size_t o = 0;
  auto alloc = [&](size_t bytes) -> void* {
    void* p = w + o;
    o += (bytes + 255) & ~(size_t)255;
    return p;
  };
  // xnf (sim GEMM input, f16) -> h1_s after simgemm
  unsigned short* xnf = (unsigned short*)alloc((size_t)N_NODES * FEAT * 2);  // 10.24 MB
  float* h1_s = (float*)xnf;
  double* rinv = (double*)alloc((size_t)N_NODES * 8);
  // r1_s region holds cap_buf until after k_knn
  float* r1_s = (float*)alloc((size_t)N_NODES * HID * 4);  // 10.24 MB
  unsigned int* cap_buf = (unsigned int*)r1_s;             // 10000*128*4 = 5.12 MB
  float* r1_t = (float*)alloc((size_t)N_NODES * HID * 4);
  float* h1_t = (float*)alloc((size_t)N_NODES * HID * 4);
  float* h2_s = (float*)alloc((size_t)N_NODES * EMB * 4);
  float* h2_t = (float*)alloc((size_t)N_NODES * EMB * 4);
  float* z_s = (float*)alloc((size_t)N_NODES * EMB * 4);
  float* z_t = (float*)alloc((size_t)N_NODES * EMB * 4);
  int* nb = (int*)alloc((size_t)N_NODES * NNB * 4);
  int* cnt_s = (int*)alloc((size_t)N_NODES * 4);
  int* off_s = (int*)alloc((size_t)(N_NODES + 1) * 4);
  int* cur_s = (int*)alloc((size_t)N_NODES * 4);
  float* dinv_s = (float*)alloc((size_t)N_NODES * 4);
  int* cnt_t = (int*)alloc((size_t)N_NODES * 4);
  int* off_t = (int*)alloc((size_t)(N_NODES + 1) * 4);
  int* cur_t = (int*)alloc((size_t)N_NODES * 4);
  float* dinv_t = (float*)alloc((size_t)N_NODES * 4);
  int* csr_s = (int*)alloc((size_t)NE_EDGES * 4);
  int* csr_t = (int*)alloc((size_t)N_NODES * NNB * 4);
  int* cnt_row = (int*)alloc((size_t)N_NODES * 4);
  int* flags = (int*)alloc((size_t)N_NODES * 4);

  const int* e_src = ei;
  const int* e_dst = ei + NE_EDGES;

  // 1. norms -> f16 normalized rows + f64 inv norms
  k_norms<<<N_NODES, 128, 0, stream>>>(x, xnf, rinv);
  // 2. zero counters (cnt_row/flags must be reset every call)
  k_zero<<<(N_NODES + 255) / 256, 256, 0, stream>>>(cnt_s, N_NODES);
  k_zero<<<(N_NODES + 255) / 256, 256, 0, stream>>>(cnt_t, N_NODES);
  k_zero<<<(N_NODES + 255) / 256, 256, 0, stream>>>(cnt_row, N_NODES);
  k_count<<<(NE_EDGES + 255) / 256, 256, 0, stream>>>(e_dst, NE_EDGES, cnt_s);
  // 3. sim GEMM + threshold filter (single launch, no sim matrix)
  {
    dim3 gg(79, 79);
    k_simgemm<<<gg, 256, 0, stream>>>(xnf, cap_buf, cnt_row);
  }
  // 4. fused select + exact f64 rescore -> 9 neighbors; fallback for flagged rows
  k_knn<<<N_NODES, 256, 0, stream>>>(x, rinv, cap_buf, cnt_row, nb, flags);
  k_fallback<<<N_NODES, 256, 0, stream>>>(x, rinv, flags, nb);
  // 5. topology degrees + scans + scatter
  k_count<<<(N_NODES * NNB + 255) / 256, 256, 0, stream>>>(nb, N_NODES * NNB, cnt_t);
  k_scan<<<1, 1024, 0, stream>>>(cnt_s, N_NODES, off_s, cur_s, dinv_s);
  k_scan<<<1, 1024, 0, stream>>>(cnt_t, N_NODES, off_t, cur_t, dinv_t);
  k_scatter_s<<<(NE_EDGES + 255) / 256, 256, 0, stream>>>(e_src, e_dst, NE_EDGES, cur_s, csr_s);
  k_scatter_t<<<(N_NODES * NNB + 255) / 256, 256, 0, stream>>>(nb, cur_t, csr_t);
  // 6. layer-1 GEMMs (h1_s aliases xnf: safe, simgemm done)
  {
    dim3 g1((N_NODES + GBM - 1) / GBM, HID / GBN);
    k_gemm<<<g1, 256, 0, stream>>>(x, W_s1, h1_s, N_NODES, FEAT, HID);
    k_gemm<<<g1, 256, 0, stream>>>(x, W_t1, h1_t, N_NODES, FEAT, HID);
  }
  // 7. layer-1 aggregation + relu (r1_s overwrites cap_buf: safe, k_knn done)
  k_agg<<<N_NODES, HID, 0, stream>>>(h1_s, b_s1, dinv_s, off_s, csr_s, r1_s, HID, 1);
  k_agg<<<N_NODES, HID, 0, stream>>>(h1_t, b_t1, dinv_t, off_t, csr_t, r1_t, HID, 1);
  // 8. layer-2 GEMMs
  {
    dim3 g2((N_NODES + GBM - 1) / GBM, EMB / GBN);
    k_gemm<<<g2, 256, 0, stream>>>(r1_s, W_s2, h2_s, N_NODES, HID, EMB);
    k_gemm<<<g2, 256, 0, stream>>>(r1_t, W_t2, h2_t, N_NODES, HID, EMB);
  }
  // 9. layer-2 aggregation
  k_agg<<<N_NODES, EMB, 0, stream>>>(h2_s, b_s2, dinv_s, off_s, csr_s, z_s, EMB, 0);
  k_agg<<<N_NODES, EMB, 0, stream>>>(h2_t, b_t2, dinv_t, off_t, csr_t, z_t, EMB, 0);
  // 10. fusion + soft assignment
  k_fuse<<<N_NODES, 128, 0, stream>>>(z_s, z_t, fw, cent, out_z, out_q);
}

// Round 6
// 513.757 us; speedup vs baseline: 9.6835x; 1.2902x over previous
//
#include <hip/hip_runtime.h>
#include <math.h>

#define N_NODES 10000
#define FEAT 512
#define HID 256
#define EMB 128
#define NC 10
#define NE_EDGES 160000
#define KTOP 10
#define NNB 9

#define CAP 128          // per-row candidate buffer capacity
#define NSEL 16          // candidates f64-rescored
#define TAU 0.11f        // store threshold (sims ~ N(0,0.0442), s10 ~ 0.19)
#define SAFE_VAL 0.12f   // need >=10 stored above this, else fallback
#define NTB 79           // 79 tiles of 128
#define NPAIR 3160       // 79*80/2 upper-triangle blocks

typedef __attribute__((ext_vector_type(8))) short short8;
typedef __attribute__((ext_vector_type(4))) float f32x4;

typedef const __attribute__((address_space(1))) unsigned int* gas1_t;
typedef __attribute__((address_space(3))) unsigned int* las3_t;

__device__ __forceinline__ void gload_lds16(const void* g, void* l) {
  __builtin_amdgcn_global_load_lds((gas1_t)g, (las3_t)l, 16, 0, 0);
}

__device__ __forceinline__ unsigned short f2h(float f) {
  _Float16 h = (_Float16)f;
  return *(unsigned short*)&h;
}
__device__ __forceinline__ float h2f(unsigned short u) {
  _Float16 h = *(_Float16*)&u;
  return (float)h;
}

// -------------------- row norms -> f16 normalized + f16 raw + f64 inv norms --------------------
__global__ void k_norms(const float* __restrict__ x, unsigned short* __restrict__ xnf,
                        unsigned short* __restrict__ xf, double* __restrict__ rinv) {
  const int row = blockIdx.x;
  const int t = threadIdx.x;  // 128
  const float* xr = x + (size_t)row * FEAT;
  double s = 0.0;
  for (int k = t; k < FEAT; k += 128) { const double v = (double)xr[k]; s += v * v; }
  __shared__ double red[128];
  red[t] = s;
  __syncthreads();
  for (int o = 64; o > 0; o >>= 1) {
    if (t < o) red[t] += red[t + o];
    __syncthreads();
  }
  const double inv = 1.0 / fmax(sqrt(red[0]), 1e-12);
  const float finv = (float)inv;
  for (int k = t; k < FEAT; k += 128) {
    const float v = xr[k];
    xnf[(size_t)row * FEAT + k] = f2h(v * finv);
    xf[(size_t)row * FEAT + k] = f2h(v);
  }
  if (t == 0) rinv[row] = inv;
}

// -------------------- weight transpose + f16: Wt[n][k] = W[k][n] --------------------
__global__ void k_wt(const float* __restrict__ W, unsigned short* __restrict__ Wt, int K, int N) {
  const int idx = blockIdx.x * 256 + threadIdx.x;
  if (idx < K * N) {
    const int n = idx / K, k = idx % K;
    Wt[idx] = f2h(W[(size_t)k * N + n]);
  }
}

// -------------------- sim GEMM (upper triangle) + threshold filter --------------------
// 3160 blocks, XCD-chunked remap, triangular decode. Each >TAU value pushed to row gr's
// list; off-diagonal blocks also push the transposed pair (gc <- gr).
// LDS: both-sides XOR swizzle (linear gload_lds dest + pre-swizzled global src + swz read).
__global__ __launch_bounds__(256) void k_simgemm(const unsigned short* __restrict__ xnf,
                                                 unsigned int* __restrict__ cap_buf,
                                                 int* __restrict__ cnt_row) {
  __shared__ __align__(16) unsigned short As[2][4096];
  __shared__ __align__(16) unsigned short Bs[2][4096];

  const int t = threadIdx.x;
  const int lane = t & 63;
  const int w = t >> 6;
  const int lr = lane & 15;
  const int lk = lane >> 4;
  const int wr = (w >> 1) * 64, wc = (w & 1) * 64;

  // XCD-chunked bijective remap (3160 = 8*395), then triangular decode (bi <= bj)
  const int bid = (blockIdx.x & 7) * 395 + (blockIdx.x >> 3);
  int bi = (int)((159.0 - sqrt(25281.0 - 8.0 * (double)bid)) * 0.5);
  while ((bi + 1) * NTB - (bi + 1) * bi / 2 <= bid) ++bi;
  while (bi * NTB - bi * (bi - 1) / 2 > bid) --bi;
  const int bj = bi + (bid - (bi * NTB - bi * (bi - 1) / 2));
  const int arow0 = bi * 128;
  const int bcol0 = bj * 128;

  auto stage = [&](int b, int k0) {
#pragma unroll
    for (int it = 0; it < 2; ++it) {
      const int slot = it * 256 + w * 64 + lane;
      const int r = slot >> 2;
      const int qs = (slot & 3) ^ ((slot >> 3) & 3);  // source swizzle
      {
        const int gr = min(arow0 + r, N_NODES - 1);
        gload_lds16(xnf + (size_t)gr * FEAT + k0 + qs * 8, &As[b][(it * 256 + w * 64) * 8]);
      }
      {
        const int gc = min(bcol0 + r, N_NODES - 1);
        gload_lds16(xnf + (size_t)gc * FEAT + k0 + qs * 8, &Bs[b][(it * 256 + w * 64) * 8]);
      }
    }
  };

  f32x4 acc[4][4];
#pragma unroll
  for (int m = 0; m < 4; ++m)
#pragma unroll
    for (int n = 0; n < 4; ++n) acc[m][n] = (f32x4){0.f, 0.f, 0.f, 0.f};

  stage(0, 0);
  __syncthreads();

  int cur = 0;
  const int NT = FEAT / 32;  // 16
  for (int kt = 0; kt < NT; ++kt) {
    if (kt + 1 < NT) stage(cur ^ 1, (kt + 1) * 32);
    const unsigned short* Ab = As[cur];
    const unsigned short* Bb = Bs[cur];
    short8 a[4], b[4];
#pragma unroll
    for (int m = 0; m < 4; ++m) {
      const int row = wr + m * 16 + lr;
      a[m] = *(const short8*)(Ab + (((row << 2) | (lk ^ ((row >> 1) & 3))) << 3));
    }
#pragma unroll
    for (int n = 0; n < 4; ++n) {
      const int row = wc + n * 16 + lr;
      b[n] = *(const short8*)(Bb + (((row << 2) | (lk ^ ((row >> 1) & 3))) << 3));
    }
#pragma unroll
    for (int m = 0; m < 4; ++m)
#pragma unroll
      for (int n = 0; n < 4; ++n)
        acc[m][n] = __builtin_amdgcn_mfma_f32_16x16x32_f16(a[m], b[n], acc[m][n], 0, 0, 0);
    __syncthreads();
    cur ^= 1;
  }

  // filter epilogue. C/D layout: col = lane&15, row = (lane>>4)*4 + reg
  const bool offdiag = (bi != bj);
#pragma unroll
  for (int m = 0; m < 4; ++m) {
    const int rb = arow0 + wr + m * 16 + lk * 4;
#pragma unroll
    for (int n = 0; n < 4; ++n) {
      const int gc = bcol0 + wc + n * 16 + lr;
      if (gc < N_NODES) {
#pragma unroll
        for (int q = 0; q < 4; ++q) {
          const float v = acc[m][n][q];
          const int gr = rb + q;
          if (v > TAU && gr < N_NODES) {
            const unsigned short hv = f2h(v);
            {
              const int pos = atomicAdd(&cnt_row[gr], 1);
              if (pos < CAP)
                cap_buf[(size_t)gr * CAP + pos] = ((unsigned)hv << 16) | (unsigned)gc;
            }
            if (offdiag) {
              const int pos = atomicAdd(&cnt_row[gc], 1);
              if (pos < CAP)
                cap_buf[(size_t)gc * CAP + pos] = ((unsigned)hv << 16) | (unsigned)gr;
            }
          }
        }
      }
    }
  }
}

// -------------------- fused select + exact f64 rescore -> 9 neighbors (set semantics) --------------------
__global__ __launch_bounds__(256) void k_knn(const float* __restrict__ x,
                                             const double* __restrict__ rinv,
                                             const unsigned int* __restrict__ cap_buf,
                                             const int* __restrict__ cnt_row,
                                             int* __restrict__ nb, int* __restrict__ flags) {
  const int i = blockIdx.x;
  const int t = threadIdx.x;
  const int lane = t & 63;
  const int wave = t >> 6;
  __shared__ unsigned pp[CAP];
  __shared__ int sel[NSEL];
  __shared__ float xi[FEAT];
  __shared__ double dsv[NSEL];
  __shared__ int safe_cnt;

  const int cnt = cnt_row[i];
  if (cnt > CAP || cnt < NSEL) {
    if (t == 0) flags[i] = 1;
    return;
  }
  if (t == 0) { flags[i] = 0; safe_cnt = 0; }
  const int L = cnt;
  if (t < L) pp[t] = cap_buf[(size_t)i * CAP + t];
  xi[t] = x[(size_t)i * FEAT + t];
  xi[t + 256] = x[(size_t)i * FEAT + t + 256];
  __syncthreads();

  if (t < L) {
    const unsigned p = pp[t];
    if (h2f((unsigned short)(p >> 16)) >= SAFE_VAL) atomicAdd(&safe_cnt, 1);
    int rk = 0;
    for (int j = 0; j < L; ++j) rk += (pp[j] > p);
    if (rk < NSEL) sel[rk] = (int)(p & 0xffffu);
  }
  __syncthreads();
  if (safe_cnt < KTOP) {
    if (t == 0) flags[i] = 1;
    return;
  }

  const double ri = rinv[i];
  const float4 v0 = *(const float4*)(xi + lane * 8);
  const float4 v1 = *(const float4*)(xi + lane * 8 + 4);
#pragma unroll
  for (int q = 0; q < 4; ++q) {
    const int c = wave * 4 + q;
    const int ci = sel[c];
    const float4* xr = (const float4*)(x + (size_t)ci * FEAT);
    const float4 u0 = xr[lane * 2];
    const float4 u1 = xr[lane * 2 + 1];
    double s = (double)u0.x * (double)v0.x + (double)u0.y * (double)v0.y +
               (double)u0.z * (double)v0.z + (double)u0.w * (double)v0.w +
               (double)u1.x * (double)v1.x + (double)u1.y * (double)v1.y +
               (double)u1.z * (double)v1.z + (double)u1.w * (double)v1.w;
#pragma unroll
    for (int off = 1; off < 64; off <<= 1) s += __shfl_xor(s, off);
    if (lane == 0) dsv[c] = s * ri * rinv[ci];
  }
  __syncthreads();

  if (t < NSEL) {
    const double v = dsv[t];
    const int id = sel[t];
    int rk = 0;
    for (int j = 0; j < NSEL; ++j)
      rk += (dsv[j] > v) || (dsv[j] == v && sel[j] < id);
    if (rk >= 1 && rk < KTOP) nb[(size_t)i * NNB + (rk - 1)] = id;
  }
}

// -------------------- fallback: exact full scan for flagged rows (expected: none) --------------------
__global__ __launch_bounds__(256) void k_fallback(const float* __restrict__ x,
                                                  const double* __restrict__ rinv,
                                                  const int* __restrict__ flags,
                                                  int* __restrict__ nb) {
  const int i = blockIdx.x;
  if (!flags[i]) return;
  const int t = threadIdx.x;
  __shared__ float xi[FEAT];
  __shared__ double cval[256];
  __shared__ double bestv[NNB];
  __shared__ int besti[NNB];
  for (int k = t; k < FEAT; k += 256) xi[k] = x[(size_t)i * FEAT + k];
  if (t < NNB) { bestv[t] = -1e300; besti[t] = 0x7fffffff; }
  __syncthreads();
  const double ri = rinv[i];
  for (int c0 = 0; c0 < N_NODES; c0 += 256) {
    const int c = c0 + t;
    double s = -1e300;
    if (c < N_NODES && c != i) {
      s = 0.0;
      for (int k = 0; k < FEAT; ++k) s += (double)xi[k] * (double)x[(size_t)c * FEAT + k];
      s *= ri * rinv[c];
    }
    cval[t] = s;
    __syncthreads();
    if (t == 0) {
      for (int j = 0; j < 256; ++j) {
        const int c2 = c0 + j;
        const double v = cval[j];
        if (v == -1e300) continue;
        int pos = NNB;
        for (int q = 0; q < NNB; ++q) {
          if (v > bestv[q] || (v == bestv[q] && c2 < besti[q])) { pos = q; break; }
        }
        if (pos < NNB) {
          for (int q = NNB - 1; q > pos; --q) { bestv[q] = bestv[q - 1]; besti[q] = besti[q - 1]; }
          bestv[pos] = v; besti[pos] = c2;
        }
      }
    }
    __syncthreads();
  }
  if (t < NNB) nb[(size_t)i * NNB + t] = besti[t];
}

// -------------------- CSR build helpers --------------------
__global__ void k_zero(int* __restrict__ p, int n) {
  const int i = blockIdx.x * blockDim.x + threadIdx.x;
  if (i < n) p[i] = 0;
}

__global__ void k_count(const int* __restrict__ dsts, int ne, int* __restrict__ cnt) {
  const int e = blockIdx.x * blockDim.x + threadIdx.x;
  if (e < ne) atomicAdd(&cnt[dsts[e]], 1);
}

__global__ void k_scan(const int* __restrict__ cnt, int n, int* __restrict__ off,
                       int* __restrict__ cur, float* __restrict__ dinv) {
  __shared__ int buf[1024];
  __shared__ int base_s;
  const int t = threadIdx.x;
  if (t == 0) base_s = 0;
  __syncthreads();
  for (int b0 = 0; b0 < n; b0 += 1024) {
    const int i = b0 + t;
    const int v = (i < n) ? cnt[i] : 0;
    buf[t] = v;
    __syncthreads();
    for (int o = 1; o < 1024; o <<= 1) {
      const int add = (t >= o) ? buf[t - o] : 0;
      __syncthreads();
      buf[t] += add;
      __syncthreads();
    }
    const int incl = buf[t];
    const int base = base_s;
    if (i < n) {
      const int excl = base + incl - v;
      off[i] = excl;
      cur[i] = excl;
      dinv[i] = rsqrtf((float)(v + 1));
    }
    __syncthreads();
    if (t == 1023) base_s = base + buf[1023];
    __syncthreads();
  }
  if (t == 0) off[n] = base_s;
}

__global__ void k_scatter_s(const int* __restrict__ src, const int* __restrict__ dst, int ne,
                            int* __restrict__ cur, int* __restrict__ csr) {
  const int e = blockIdx.x * blockDim.x + threadIdx.x;
  if (e < ne) {
    const int p = atomicAdd(&cur[dst[e]], 1);
    csr[p] = src[e];
  }
}

__global__ void k_scatter_t(const int* __restrict__ nb, int* __restrict__ cur,
                            int* __restrict__ csr) {
  const int e = blockIdx.x * blockDim.x + threadIdx.x;
  if (e < N_NODES * NNB) {
    const int i = e / NNB;
    const int v = nb[e];
    const int p = atomicAdd(&cur[v], 1);
    csr[p] = i;
  }
}

// -------------------- f16 MFMA feature GEMM: C[MxN] = A[MxK] @ Bt[NxK]^T --------------------
__global__ __launch_bounds__(256) void k_fgemm(const unsigned short* __restrict__ A,
                                               const unsigned short* __restrict__ Bt,
                                               float* __restrict__ C, int M, int K, int N) {
  __shared__ __align__(16) unsigned short As[2][4096];
  __shared__ __align__(16) unsigned short Bs[2][4096];
  const int t = threadIdx.x;
  const int lane = t & 63, w = t >> 6;
  const int lr = lane & 15, lk = lane >> 4;
  const int wr = (w >> 1) * 64, wc = (w & 1) * 64;
  const int arow0 = blockIdx.x * 128, bcol0 = blockIdx.y * 128;

  auto stage = [&](int b, int k0) {
#pragma unroll
    for (int it = 0; it < 2; ++it) {
      const int slot = it * 256 + w * 64 + lane;
      const int r = slot >> 2;
      const int qs = (slot & 3) ^ ((slot >> 3) & 3);
      {
        const int gr = min(arow0 + r, M - 1);
        gload_lds16(A + (size_t)gr * K + k0 + qs * 8, &As[b][(it * 256 + w * 64) * 8]);
      }
      {
        const int gc = min(bcol0 + r, N - 1);
        gload_lds16(Bt + (size_t)gc * K + k0 + qs * 8, &Bs[b][(it * 256 + w * 64) * 8]);
      }
    }
  };

  f32x4 acc[4][4];
#pragma unroll
  for (int m = 0; m < 4; ++m)
#pragma unroll
    for (int n = 0; n < 4; ++n) acc[m][n] = (f32x4){0.f, 0.f, 0.f, 0.f};

  stage(0, 0);
  __syncthreads();

  int cur = 0;
  const int NT = K >> 5;
  for (int kt = 0; kt < NT; ++kt) {
    if (kt + 1 < NT) stage(cur ^ 1, (kt + 1) << 5);
    const unsigned short* Ab = As[cur];
    const unsigned short* Bb = Bs[cur];
    short8 a[4], b[4];
#pragma unroll
    for (int m = 0; m < 4; ++m) {
      const int row = wr + m * 16 + lr;
      a[m] = *(const short8*)(Ab + (((row << 2) | (lk ^ ((row >> 1) & 3))) << 3));
    }
#pragma unroll
    for (int n = 0; n < 4; ++n) {
      const int row = wc + n * 16 + lr;
      b[n] = *(const short8*)(Bb + (((row << 2) | (lk ^ ((row >> 1) & 3))) << 3));
    }
#pragma unroll
    for (int m = 0; m < 4; ++m)
#pragma unroll
      for (int n = 0; n < 4; ++n)
        acc[m][n] = __builtin_amdgcn_mfma_f32_16x16x32_f16(a[m], b[n], acc[m][n], 0, 0, 0);
    __syncthreads();
    cur ^= 1;
  }

#pragma unroll
  for (int m = 0; m < 4; ++m) {
    const int rb = arow0 + wr + m * 16 + lk * 4;
#pragma unroll
    for (int n = 0; n < 4; ++n) {
      const int gc = bcol0 + wc + n * 16 + lr;
#pragma unroll
      for (int q = 0; q < 4; ++q) {
        const int gm = rb + q;
        if (gm < M) C[(size_t)gm * N + gc] = acc[m][n][q];
      }
    }
  }
}

// -------------------- GCN aggregation (f32 in, f16 out, relu) for layer-1 --------------------
__global__ void k_agg_h(const float* __restrict__ h, const float* __restrict__ bias,
                        const float* __restrict__ dinv, const int* __restrict__ off,
                        const int* __restrict__ csr, unsigned short* __restrict__ out) {
  const int v = blockIdx.x;
  const int c = threadIdx.x;  // HID
  const float dv = dinv[v];
  float acc = h[(size_t)v * HID + c] * dv;
  const int s0 = off[v], s1 = off[v + 1];
  for (int e = s0; e < s1; ++e) {
    const int s = csr[e];
    acc += h[(size_t)s * HID + c] * dinv[s];
  }
  acc = acc * dv + bias[c];
  out[(size_t)v * HID + c] = f2h(fmaxf(acc, 0.f));
}

// -------------------- GCN aggregation (f32 in/out) for layer-2 --------------------
__global__ void k_agg(const float* __restrict__ h, const float* __restrict__ bias,
                      const float* __restrict__ dinv, const int* __restrict__ off,
                      const int* __restrict__ csr, float* __restrict__ out) {
  const int v = blockIdx.x;
  const int c = threadIdx.x;  // EMB
  const float dv = dinv[v];
  float acc = h[(size_t)v * EMB + c] * dv;
  const int s0 = off[v], s1 = off[v + 1];
  for (int e = s0; e < s1; ++e) {
    const int s = csr[e];
    acc += h[(size_t)s * EMB + c] * dinv[s];
  }
  out[(size_t)v * EMB + c] = acc * dv + bias[c];
}

// -------------------- fusion + Student-t soft assignment --------------------
__global__ void k_fuse(const float* __restrict__ zs, const float* __restrict__ zt,
                       const float* __restrict__ fw, const float* __restrict__ cent,
                       float* __restrict__ out_z, float* __restrict__ out_q) {
  const int v = blockIdx.x;
  const int t = threadIdx.x;  // 128
  __shared__ float zsh[EMB];
  __shared__ float cs[NC][EMB];
  __shared__ float qv[NC];
  __shared__ float qs;
  for (int k = t; k < NC * EMB; k += 128) ((float*)cs)[k] = cent[k];
  const float beta = 1.f / (1.f + expf(-fw[0]));
  const float z = beta * zs[(size_t)v * EMB + t] + (1.f - beta) * zt[(size_t)v * EMB + t];
  out_z[(size_t)v * EMB + t] = z;
  zsh[t] = z;
  __syncthreads();
  if (t < NC) {
    float s = 0.f;
    for (int c = 0; c < EMB; ++c) {
      const float d = zsh[c] - cs[t][c];
      s += d * d;
    }
    qv[t] = 1.f / (1.f + s);
  }
  __syncthreads();
  if (t == 0) {
    float s = 0.f;
    for (int k = 0; k < NC; ++k) s += qv[k];
    qs = s;
  }
  __syncthreads();
  if (t < NC) out_q[(size_t)v * NC + t] = qv[t] / qs;
}

extern "C" void kernel_launch(void* const* d_in, const int* in_sizes, int n_in, void* d_out,
                              int out_size, void* d_ws, size_t ws_size, hipStream_t stream) {
  const float* x = (const float*)d_in[0];
  const int* ei = (const int*)d_in[1];
  const float* W_s1 = (const float*)d_in[2];
  const float* b_s1 = (const float*)d_in[3];
  const float* W_s2 = (const float*)d_in[4];
  const float* b_s2 = (const float*)d_in[5];
  const float* W_t1 = (const float*)d_in[6];
  const float* b_t1 = (const float*)d_in[7];
  const float* W_t2 = (const float*)d_in[8];
  const float* b_t2 = (const float*)d_in[9];
  const float* fw = (const float*)d_in[10];
  const float* cent = (const float*)d_in[11];
  float* out_z = (float*)d_out;
  float* out_q = out_z + (size_t)N_NODES * EMB;

  char* w = (char*)d_ws;
  size_t o = 0;
  auto alloc = [&](size_t bytes) -> void* {
    void* p = w + o;
    o += (bytes + 255) & ~(size_t)255;
    return p;
  };
  // xnf (normalized f16, simgemm input) -> h1_s f32 after simgemm (both 10.24 MB)
  unsigned short* xnf = (unsigned short*)alloc((size_t)N_NODES * FEAT * 2);
  float* h1_s = (float*)xnf;
  // xf (raw f16, layer-1 GEMM input) -> h2_s/h2_t f32 after layer-1 GEMMs (10.24 MB)
  unsigned short* xf = (unsigned short*)alloc((size_t)N_NODES * FEAT * 2);
  float* h2_s = (float*)xf;
  float* h2_t = (float*)xf + (size_t)N_NODES * EMB;
  double* rinv = (double*)alloc((size_t)N_NODES * 8);
  // cap_buf (5.12 MB) -> r1_s f16 after k_knn (both 5.12 MB)
  unsigned int* cap_buf = (unsigned int*)alloc((size_t)N_NODES * CAP * 4);
  unsigned short* r1_s = (unsigned short*)cap_buf;
  unsigned short* r1_t = (unsigned short*)alloc((size_t)N_NODES * HID * 2);
  float* h1_t = (float*)alloc((size_t)N_NODES * HID * 4);
  float* z_s = (float*)alloc((size_t)N_NODES * EMB * 4);
  float* z_t = (float*)alloc((size_t)N_NODES * EMB * 4);
  int* nb = (int*)alloc((size_t)N_NODES * NNB * 4);
  int* cnt_s = (int*)alloc((size_t)N_NODES * 4);
  int* off_s = (int*)alloc((size_t)(N_NODES + 1) * 4);
  int* cur_s = (int*)alloc((size_t)N_NODES * 4);
  float* dinv_s = (float*)alloc((size_t)N_NODES * 4);
  int* cnt_t = (int*)alloc((size_t)N_NODES * 4);
  int* off_t = (int*)alloc((size_t)(N_NODES + 1) * 4);
  int* cur_t = (int*)alloc((size_t)N_NODES * 4);
  float* dinv_t = (float*)alloc((size_t)N_NODES * 4);
  int* csr_s = (int*)alloc((size_t)NE_EDGES * 4);
  int* csr_t = (int*)alloc((size_t)N_NODES * NNB * 4);
  int* cnt_row = (int*)alloc((size_t)N_NODES * 4);
  int* flags = (int*)alloc((size_t)N_NODES * 4);
  unsigned short* Wt_s1 = (unsigned short*)alloc((size_t)FEAT * HID * 2);
  unsigned short* Wt_t1 = (unsigned short*)alloc((size_t)FEAT * HID * 2);
  unsigned short* Wt_s2 = (unsigned short*)alloc((size_t)HID * EMB * 2);
  unsigned short* Wt_t2 = (unsigned short*)alloc((size_t)HID * EMB * 2);

  const int* e_src = ei;
  const int* e_dst = ei + NE_EDGES;

  // 1. norms -> f16 normalized + f16 raw + f64 inv norms; weight transposes
  k_norms<<<N_NODES, 128, 0, stream>>>(x, xnf, xf, rinv);
  k_wt<<<(FEAT * HID + 255) / 256, 256, 0, stream>>>(W_s1, Wt_s1, FEAT, HID);
  k_wt<<<(FEAT * HID + 255) / 256, 256, 0, stream>>>(W_t1, Wt_t1, FEAT, HID);
  k_wt<<<(HID * EMB + 255) / 256, 256, 0, stream>>>(W_s2, Wt_s2, HID, EMB);
  k_wt<<<(HID * EMB + 255) / 256, 256, 0, stream>>>(W_t2, Wt_t2, HID, EMB);
  // 2. zero counters
  k_zero<<<(N_NODES + 255) / 256, 256, 0, stream>>>(cnt_s, N_NODES);
  k_zero<<<(N_NODES + 255) / 256, 256, 0, stream>>>(cnt_t, N_NODES);
  k_zero<<<(N_NODES + 255) / 256, 256, 0, stream>>>(cnt_row, N_NODES);
  k_count<<<(NE_EDGES + 255) / 256, 256, 0, stream>>>(e_dst, NE_EDGES, cnt_s);
  // 3. sim GEMM (upper triangle, XCD-chunked) + threshold filter
  k_simgemm<<<NPAIR, 256, 0, stream>>>(xnf, cap_buf, cnt_row);
  // 4. fused select + exact f64 rescore -> 9 neighbors; fallback for flagged rows
  k_knn<<<N_NODES, 256, 0, stream>>>(x, rinv, cap_buf, cnt_row, nb, flags);
  k_fallback<<<N_NODES, 256, 0, stream>>>(x, rinv, flags, nb);
  // 5. topology degrees + scans + scatter
  k_count<<<(N_NODES * NNB + 255) / 256, 256, 0, stream>>>(nb, N_NODES * NNB, cnt_t);
  k_scan<<<1, 1024, 0, stream>>>(cnt_s, N_NODES, off_s, cur_s, dinv_s);
  k_scan<<<1, 1024, 0, stream>>>(cnt_t, N_NODES, off_t, cur_t, dinv_t);
  k_scatter_s<<<(NE_EDGES + 255) / 256, 256, 0, stream>>>(e_src, e_dst, NE_EDGES, cur_s, csr_s);
  k_scatter_t<<<(N_NODES * NNB + 255) / 256, 256, 0, stream>>>(nb, cur_t, csr_t);
  // 6. layer-1 f16 MFMA GEMMs (h1_s aliases xnf: safe, simgemm done)
  {
    dim3 g1(NTB, HID / 128);
    k_fgemm<<<g1, 256, 0, stream>>>(xf, Wt_s1, h1_s, N_NODES, FEAT, HID);
    k_fgemm<<<g1, 256, 0, stream>>>(xf, Wt_t1, h1_t, N_NODES, FEAT, HID);
  }
  // 7. layer-1 aggregation + relu -> f16 r1 (r1_s overwrites cap_buf: safe, k_knn done)
  k_agg_h<<<N_NODES, HID, 0, stream>>>(h1_s, b_s1, dinv_s, off_s, csr_s, r1_s);
  k_agg_h<<<N_NODES, HID, 0, stream>>>(h1_t, b_t1, dinv_t, off_t, csr_t, r1_t);
  // 8. layer-2 f16 MFMA GEMMs (h2_s/h2_t alias xf: safe, layer-1 GEMMs done)
  {
    dim3 g2(NTB, EMB / 128);
    k_fgemm<<<g2, 256, 0, stream>>>(r1_s, Wt_s2, h2_s, N_NODES, HID, EMB);
    k_fgemm<<<g2, 256, 0, stream>>>(r1_t, Wt_t2, h2_t, N_NODES, HID, EMB);
  }
  // 9. layer-2 aggregation
  k_agg<<<N_NODES, EMB, 0, stream>>>(h2_s, b_s2, dinv_s, off_s, csr_s, z_s);
  k_agg<<<N_NODES, EMB, 0, stream>>>(h2_t, b_t2, dinv_t, off_t, csr_t, z_t);
  // 10. fusion + soft assignment
  k_fuse<<<N_NODES, 128, 0, stream>>>(z_s, z_t, fw, cent, out_z, out_q);
}

// Round 7
// 480.921 us; speedup vs baseline: 10.3447x; 1.0683x over previous
//
#include <hip/hip_runtime.h>
#include <math.h>

#define N_NODES 10000
#define FEAT 512
#define HID 256
#define EMB 128
#define NC 10
#define NE_EDGES 160000
#define KTOP 10
#define NNB 9

#define CAP 128          // per-row candidate buffer capacity
#define NSEL 16          // candidates f64-rescored
#define TAU 0.11f        // store threshold (sims ~ N(0,0.0442), s10 ~ 0.19)
#define SAFE_VAL 0.12f   // need >=10 stored above this, else fallback
#define NTB 79           // 79 tiles of 128
#define NPAIR 3160       // 79*80/2 upper-triangle blocks

typedef __attribute__((ext_vector_type(8))) short short8;
typedef __attribute__((ext_vector_type(4))) float f32x4;

typedef const __attribute__((address_space(1))) unsigned int* gas1_t;
typedef __attribute__((address_space(3))) unsigned int* las3_t;

__device__ __forceinline__ void gload_lds16(const void* g, void* l) {
  __builtin_amdgcn_global_load_lds((gas1_t)g, (las3_t)l, 16, 0, 0);
}

__device__ __forceinline__ unsigned short f2h(float f) {
  _Float16 h = (_Float16)f;
  return *(unsigned short*)&h;
}
__device__ __forceinline__ float h2f(unsigned short u) {
  _Float16 h = *(_Float16*)&u;
  return (float)h;
}

// -------------------- row norms -> f16 normalized + f16 raw + f64 inv norms --------------------
__global__ void k_norms(const float* __restrict__ x, unsigned short* __restrict__ xnf,
                        unsigned short* __restrict__ xf, double* __restrict__ rinv) {
  const int row = blockIdx.x;
  const int t = threadIdx.x;  // 128
  const float* xr = x + (size_t)row * FEAT;
  double s = 0.0;
  for (int k = t; k < FEAT; k += 128) { const double v = (double)xr[k]; s += v * v; }
  __shared__ double red[128];
  red[t] = s;
  __syncthreads();
  for (int o = 64; o > 0; o >>= 1) {
    if (t < o) red[t] += red[t + o];
    __syncthreads();
  }
  const double inv = 1.0 / fmax(sqrt(red[0]), 1e-12);
  const float finv = (float)inv;
  for (int k = t; k < FEAT; k += 128) {
    const float v = xr[k];
    xnf[(size_t)row * FEAT + k] = f2h(v * finv);
    xf[(size_t)row * FEAT + k] = f2h(v);
  }
  if (t == 0) rinv[row] = inv;
}

// -------------------- weight transpose + f16: Wt[n][k] = W[k][n] --------------------
__global__ void k_wt(const float* __restrict__ W, unsigned short* __restrict__ Wt, int K, int N) {
  const int idx = blockIdx.x * 256 + threadIdx.x;
  if (idx < K * N) {
    const int n = idx / K, k = idx % K;
    Wt[idx] = f2h(W[(size_t)k * N + n]);
  }
}

// -------------------- sim GEMM (upper triangle) + threshold filter --------------------
// Counted-vmcnt pipeline (T4): next tile's 4 loads/wave stay in flight across the barrier;
// vmcnt(4) waits exactly for the current tile (its loads are the 4 oldest).
__global__ __launch_bounds__(256) void k_simgemm(const unsigned short* __restrict__ xnf,
                                                 unsigned int* __restrict__ cap_buf,
                                                 int* __restrict__ cnt_row) {
  __shared__ __align__(16) unsigned short As[2][4096];
  __shared__ __align__(16) unsigned short Bs[2][4096];

  const int t = threadIdx.x;
  const int lane = t & 63;
  const int w = t >> 6;
  const int lr = lane & 15;
  const int lk = lane >> 4;
  const int wr = (w >> 1) * 64, wc = (w & 1) * 64;

  // XCD-chunked bijective remap (3160 = 8*395), then triangular decode (bi <= bj)
  const int bid = (blockIdx.x & 7) * 395 + (blockIdx.x >> 3);
  int bi = (int)((159.0 - sqrt(25281.0 - 8.0 * (double)bid)) * 0.5);
  while ((bi + 1) * NTB - (bi + 1) * bi / 2 <= bid) ++bi;
  while (bi * NTB - bi * (bi - 1) / 2 > bid) --bi;
  const int bj = bi + (bid - (bi * NTB - bi * (bi - 1) / 2));
  const int arow0 = bi * 128;
  const int bcol0 = bj * 128;

  auto stage = [&](int b, int k0) {
#pragma unroll
    for (int it = 0; it < 2; ++it) {
      const int slot = it * 256 + w * 64 + lane;
      const int r = slot >> 2;
      const int qs = (slot & 3) ^ ((slot >> 3) & 3);  // source swizzle
      {
        const int gr = min(arow0 + r, N_NODES - 1);
        gload_lds16(xnf + (size_t)gr * FEAT + k0 + qs * 8, &As[b][(it * 256 + w * 64) * 8]);
      }
      {
        const int gc = min(bcol0 + r, N_NODES - 1);
        gload_lds16(xnf + (size_t)gc * FEAT + k0 + qs * 8, &Bs[b][(it * 256 + w * 64) * 8]);
      }
    }
  };

  f32x4 acc[4][4];
#pragma unroll
  for (int m = 0; m < 4; ++m)
#pragma unroll
    for (int n = 0; n < 4; ++n) acc[m][n] = (f32x4){0.f, 0.f, 0.f, 0.f};

  stage(0, 0);

  const int NT = FEAT / 32;  // 16
  for (int kt = 0; kt < NT; ++kt) {
    const int cur = kt & 1;
    if (kt + 1 < NT) {
      stage(cur ^ 1, (kt + 1) * 32);
      asm volatile("s_waitcnt vmcnt(4)" ::: "memory");
    } else {
      asm volatile("s_waitcnt vmcnt(0)" ::: "memory");
    }
    __builtin_amdgcn_s_barrier();
    asm volatile("" ::: "memory");
    const unsigned short* Ab = As[cur];
    const unsigned short* Bb = Bs[cur];
    short8 a[4], b[4];
#pragma unroll
    for (int m = 0; m < 4; ++m) {
      const int row = wr + m * 16 + lr;
      a[m] = *(const short8*)(Ab + (((row << 2) | (lk ^ ((row >> 1) & 3))) << 3));
    }
#pragma unroll
    for (int n = 0; n < 4; ++n) {
      const int row = wc + n * 16 + lr;
      b[n] = *(const short8*)(Bb + (((row << 2) | (lk ^ ((row >> 1) & 3))) << 3));
    }
#pragma unroll
    for (int m = 0; m < 4; ++m)
#pragma unroll
      for (int n = 0; n < 4; ++n)
        acc[m][n] = __builtin_amdgcn_mfma_f32_16x16x32_f16(a[m], b[n], acc[m][n], 0, 0, 0);
    asm volatile("" ::: "memory");
    if (kt + 1 < NT) __builtin_amdgcn_s_barrier();
  }

  // filter epilogue. C/D layout: col = lane&15, row = (lane>>4)*4 + reg
  const bool offdiag = (bi != bj);
#pragma unroll
  for (int m = 0; m < 4; ++m) {
    const int rb = arow0 + wr + m * 16 + lk * 4;
#pragma unroll
    for (int n = 0; n < 4; ++n) {
      const int gc = bcol0 + wc + n * 16 + lr;
      if (gc < N_NODES) {
#pragma unroll
        for (int q = 0; q < 4; ++q) {
          const float v = acc[m][n][q];
          const int gr = rb + q;
          if (v > TAU && gr < N_NODES) {
            const unsigned short hv = f2h(v);
            {
              const int pos = atomicAdd(&cnt_row[gr], 1);
              if (pos < CAP)
                cap_buf[(size_t)gr * CAP + pos] = ((unsigned)hv << 16) | (unsigned)gc;
            }
            if (offdiag) {
              const int pos = atomicAdd(&cnt_row[gc], 1);
              if (pos < CAP)
                cap_buf[(size_t)gc * CAP + pos] = ((unsigned)hv << 16) | (unsigned)gr;
            }
          }
        }
      }
    }
  }
}

// -------------------- fused select + exact f64 rescore -> 9 neighbors (set semantics) --------------------
__global__ __launch_bounds__(256) void k_knn(const float* __restrict__ x,
                                             const double* __restrict__ rinv,
                                             const unsigned int* __restrict__ cap_buf,
                                             const int* __restrict__ cnt_row,
                                             int* __restrict__ nb, int* __restrict__ flags) {
  const int i = blockIdx.x;
  const int t = threadIdx.x;
  const int lane = t & 63;
  const int wave = t >> 6;
  __shared__ unsigned pp[CAP];
  __shared__ int sel[NSEL];
  __shared__ float xi[FEAT];
  __shared__ double dsv[NSEL];
  __shared__ int safe_cnt;

  const int cnt = cnt_row[i];
  if (cnt > CAP || cnt < NSEL) {
    if (t == 0) flags[i] = 1;
    return;
  }
  if (t == 0) { flags[i] = 0; safe_cnt = 0; }
  const int L = cnt;
  if (t < L) pp[t] = cap_buf[(size_t)i * CAP + t];
  xi[t] = x[(size_t)i * FEAT + t];
  xi[t + 256] = x[(size_t)i * FEAT + t + 256];
  __syncthreads();

  if (t < L) {
    const unsigned p = pp[t];
    if (h2f((unsigned short)(p >> 16)) >= SAFE_VAL) atomicAdd(&safe_cnt, 1);
    int rk = 0;
    for (int j = 0; j < L; ++j) rk += (pp[j] > p);
    if (rk < NSEL) sel[rk] = (int)(p & 0xffffu);
  }
  __syncthreads();
  if (safe_cnt < KTOP) {
    if (t == 0) flags[i] = 1;
    return;
  }

  const double ri = rinv[i];
  const float4 v0 = *(const float4*)(xi + lane * 8);
  const float4 v1 = *(const float4*)(xi + lane * 8 + 4);
#pragma unroll
  for (int q = 0; q < 4; ++q) {
    const int c = wave * 4 + q;
    const int ci = sel[c];
    const float4* xr = (const float4*)(x + (size_t)ci * FEAT);
    const float4 u0 = xr[lane * 2];
    const float4 u1 = xr[lane * 2 + 1];
    double s = (double)u0.x * (double)v0.x + (double)u0.y * (double)v0.y +
               (double)u0.z * (double)v0.z + (double)u0.w * (double)v0.w +
               (double)u1.x * (double)v1.x + (double)u1.y * (double)v1.y +
               (double)u1.z * (double)v1.z + (double)u1.w * (double)v1.w;
#pragma unroll
    for (int off = 1; off < 64; off <<= 1) s += __shfl_xor(s, off);
    if (lane == 0) dsv[c] = s * ri * rinv[ci];
  }
  __syncthreads();

  if (t < NSEL) {
    const double v = dsv[t];
    const int id = sel[t];
    int rk = 0;
    for (int j = 0; j < NSEL; ++j)
      rk += (dsv[j] > v) || (dsv[j] == v && sel[j] < id);
    if (rk >= 1 && rk < KTOP) nb[(size_t)i * NNB + (rk - 1)] = id;
  }
}

// -------------------- fallback: exact full scan for flagged rows (expected: none) --------------------
__global__ __launch_bounds__(256) void k_fallback(const float* __restrict__ x,
                                                  const double* __restrict__ rinv,
                                                  const int* __restrict__ flags,
                                                  int* __restrict__ nb) {
  const int i = blockIdx.x;
  if (!flags[i]) return;
  const int t = threadIdx.x;
  __shared__ float xi[FEAT];
  __shared__ double cval[256];
  __shared__ double bestv[NNB];
  __shared__ int besti[NNB];
  for (int k = t; k < FEAT; k += 256) xi[k] = x[(size_t)i * FEAT + k];
  if (t < NNB) { bestv[t] = -1e300; besti[t] = 0x7fffffff; }
  __syncthreads();
  const double ri = rinv[i];
  for (int c0 = 0; c0 < N_NODES; c0 += 256) {
    const int c = c0 + t;
    double s = -1e300;
    if (c < N_NODES && c != i) {
      s = 0.0;
      for (int k = 0; k < FEAT; ++k) s += (double)xi[k] * (double)x[(size_t)c * FEAT + k];
      s *= ri * rinv[c];
    }
    cval[t] = s;
    __syncthreads();
    if (t == 0) {
      for (int j = 0; j < 256; ++j) {
        const int c2 = c0 + j;
        const double v = cval[j];
        if (v == -1e300) continue;
        int pos = NNB;
        for (int q = 0; q < NNB; ++q) {
          if (v > bestv[q] || (v == bestv[q] && c2 < besti[q])) { pos = q; break; }
        }
        if (pos < NNB) {
          for (int q = NNB - 1; q > pos; --q) { bestv[q] = bestv[q - 1]; besti[q] = besti[q - 1]; }
          bestv[pos] = v; besti[pos] = c2;
        }
      }
    }
    __syncthreads();
  }
  if (t < NNB) nb[(size_t)i * NNB + t] = besti[t];
}

// -------------------- CSR build helpers --------------------
__global__ void k_zero(int* __restrict__ p, int n) {
  const int i = blockIdx.x * blockDim.x + threadIdx.x;
  if (i < n) p[i] = 0;
}

__global__ void k_count(const int* __restrict__ dsts, int ne, int* __restrict__ cnt) {
  const int e = blockIdx.x * blockDim.x + threadIdx.x;
  if (e < ne) atomicAdd(&cnt[dsts[e]], 1);
}

__global__ void k_scan(const int* __restrict__ cnt, int n, int* __restrict__ off,
                       int* __restrict__ cur, float* __restrict__ dinv) {
  __shared__ int buf[1024];
  __shared__ int base_s;
  const int t = threadIdx.x;
  if (t == 0) base_s = 0;
  __syncthreads();
  for (int b0 = 0; b0 < n; b0 += 1024) {
    const int i = b0 + t;
    const int v = (i < n) ? cnt[i] : 0;
    buf[t] = v;
    __syncthreads();
    for (int o = 1; o < 1024; o <<= 1) {
      const int add = (t >= o) ? buf[t - o] : 0;
      __syncthreads();
      buf[t] += add;
      __syncthreads();
    }
    const int incl = buf[t];
    const int base = base_s;
    if (i < n) {
      const int excl = base + incl - v;
      off[i] = excl;
      cur[i] = excl;
      dinv[i] = rsqrtf((float)(v + 1));
    }
    __syncthreads();
    if (t == 1023) base_s = base + buf[1023];
    __syncthreads();
  }
  if (t == 0) off[n] = base_s;
}

__global__ void k_scatter_s(const int* __restrict__ src, const int* __restrict__ dst, int ne,
                            int* __restrict__ cur, int* __restrict__ csr) {
  const int e = blockIdx.x * blockDim.x + threadIdx.x;
  if (e < ne) {
    const int p = atomicAdd(&cur[dst[e]], 1);
    csr[p] = src[e];
  }
}

__global__ void k_scatter_t(const int* __restrict__ nb, int* __restrict__ cur,
                            int* __restrict__ csr) {
  const int e = blockIdx.x * blockDim.x + threadIdx.x;
  if (e < N_NODES * NNB) {
    const int i = e / NNB;
    const int v = nb[e];
    const int p = atomicAdd(&cur[v], 1);
    csr[p] = i;
  }
}

// -------------------- f16 MFMA feature GEMM (merged pair): C = A @ Bt^T --------------------
// blockIdx.y in [0, 2*N/128): half = by/(N/128) selects the (A,Bt,C) triple.
__global__ __launch_bounds__(256) void k_fgemm2(const unsigned short* __restrict__ A0,
                                                const unsigned short* __restrict__ A1,
                                                const unsigned short* __restrict__ Bt0,
                                                const unsigned short* __restrict__ Bt1,
                                                float* __restrict__ C0, float* __restrict__ C1,
                                                int M, int K, int N) {
  __shared__ __align__(16) unsigned short As[2][4096];
  __shared__ __align__(16) unsigned short Bs[2][4096];
  const int t = threadIdx.x;
  const int lane = t & 63, w = t >> 6;
  const int lr = lane & 15, lk = lane >> 4;
  const int wr = (w >> 1) * 64, wc = (w & 1) * 64;
  const int nbn = N >> 7;
  const int half = blockIdx.y / nbn;
  const unsigned short* A = half ? A1 : A0;
  const unsigned short* Bt = half ? Bt1 : Bt0;
  float* C = half ? C1 : C0;
  const int arow0 = blockIdx.x * 128, bcol0 = (blockIdx.y % nbn) * 128;

  auto stage = [&](int b, int k0) {
#pragma unroll
    for (int it = 0; it < 2; ++it) {
      const int slot = it * 256 + w * 64 + lane;
      const int r = slot >> 2;
      const int qs = (slot & 3) ^ ((slot >> 3) & 3);
      {
        const int gr = min(arow0 + r, M - 1);
        gload_lds16(A + (size_t)gr * K + k0 + qs * 8, &As[b][(it * 256 + w * 64) * 8]);
      }
      {
        const int gc = min(bcol0 + r, N - 1);
        gload_lds16(Bt + (size_t)gc * K + k0 + qs * 8, &Bs[b][(it * 256 + w * 64) * 8]);
      }
    }
  };

  f32x4 acc[4][4];
#pragma unroll
  for (int m = 0; m < 4; ++m)
#pragma unroll
    for (int n = 0; n < 4; ++n) acc[m][n] = (f32x4){0.f, 0.f, 0.f, 0.f};

  stage(0, 0);

  const int NT = K >> 5;
  for (int kt = 0; kt < NT; ++kt) {
    const int cur = kt & 1;
    if (kt + 1 < NT) {
      stage(cur ^ 1, (kt + 1) << 5);
      asm volatile("s_waitcnt vmcnt(4)" ::: "memory");
    } else {
      asm volatile("s_waitcnt vmcnt(0)" ::: "memory");
    }
    __builtin_amdgcn_s_barrier();
    asm volatile("" ::: "memory");
    const unsigned short* Ab = As[cur];
    const unsigned short* Bb = Bs[cur];
    short8 a[4], b[4];
#pragma unroll
    for (int m = 0; m < 4; ++m) {
      const int row = wr + m * 16 + lr;
      a[m] = *(const short8*)(Ab + (((row << 2) | (lk ^ ((row >> 1) & 3))) << 3));
    }
#pragma unroll
    for (int n = 0; n < 4; ++n) {
      const int row = wc + n * 16 + lr;
      b[n] = *(const short8*)(Bb + (((row << 2) | (lk ^ ((row >> 1) & 3))) << 3));
    }
#pragma unroll
    for (int m = 0; m < 4; ++m)
#pragma unroll
      for (int n = 0; n < 4; ++n)
        acc[m][n] = __builtin_amdgcn_mfma_f32_16x16x32_f16(a[m], b[n], acc[m][n], 0, 0, 0);
    asm volatile("" ::: "memory");
    if (kt + 1 < NT) __builtin_amdgcn_s_barrier();
  }

#pragma unroll
  for (int m = 0; m < 4; ++m) {
    const int rb = arow0 + wr + m * 16 + lk * 4;
#pragma unroll
    for (int n = 0; n < 4; ++n) {
      const int gc = bcol0 + wc + n * 16 + lr;
#pragma unroll
      for (int q = 0; q < 4; ++q) {
        const int gm = rb + q;
        if (gm < M) C[(size_t)gm * N + gc] = acc[m][n][q];
      }
    }
  }
}

// -------------------- GCN aggregation (f32 in, f16 out, relu) for layer-1 --------------------
__global__ void k_agg_h(const float* __restrict__ h, const float* __restrict__ bias,
                        const float* __restrict__ dinv, const int* __restrict__ off,
                        const int* __restrict__ csr, unsigned short* __restrict__ out) {
  const int v = blockIdx.x;
  const int c = threadIdx.x;  // HID
  const float dv = dinv[v];
  float acc = h[(size_t)v * HID + c] * dv;
  const int s0 = off[v], s1 = off[v + 1];
  for (int e = s0; e < s1; ++e) {
    const int s = csr[e];
    acc += h[(size_t)s * HID + c] * dinv[s];
  }
  acc = acc * dv + bias[c];
  out[(size_t)v * HID + c] = f2h(fmaxf(acc, 0.f));
}

// -------------------- GCN aggregation (f32 in/out) for layer-2 --------------------
__global__ void k_agg(const float* __restrict__ h, const float* __restrict__ bias,
                      const float* __restrict__ dinv, const int* __restrict__ off,
                      const int* __restrict__ csr, float* __restrict__ out) {
  const int v = blockIdx.x;
  const int c = threadIdx.x;  // EMB
  const float dv = dinv[v];
  float acc = h[(size_t)v * EMB + c] * dv;
  const int s0 = off[v], s1 = off[v + 1];
  for (int e = s0; e < s1; ++e) {
    const int s = csr[e];
    acc += h[(size_t)s * EMB + c] * dinv[s];
  }
  out[(size_t)v * EMB + c] = acc * dv + bias[c];
}

// -------------------- fusion + Student-t soft assignment --------------------
__global__ void k_fuse(const float* __restrict__ zs, const float* __restrict__ zt,
                       const float* __restrict__ fw, const float* __restrict__ cent,
                       float* __restrict__ out_z, float* __restrict__ out_q) {
  const int v = blockIdx.x;
  const int t = threadIdx.x;  // 128
  __shared__ float zsh[EMB];
  __shared__ float cs[NC][EMB];
  __shared__ float qv[NC];
  __shared__ float qs;
  for (int k = t; k < NC * EMB; k += 128) ((float*)cs)[k] = cent[k];
  const float beta = 1.f / (1.f + expf(-fw[0]));
  const float z = beta * zs[(size_t)v * EMB + t] + (1.f - beta) * zt[(size_t)v * EMB + t];
  out_z[(size_t)v * EMB + t] = z;
  zsh[t] = z;
  __syncthreads();
  if (t < NC) {
    float s = 0.f;
    for (int c = 0; c < EMB; ++c) {
      const float d = zsh[c] - cs[t][c];
      s += d * d;
    }
    qv[t] = 1.f / (1.f + s);
  }
  __syncthreads();
  if (t == 0) {
    float s = 0.f;
    for (int k = 0; k < NC; ++k) s += qv[k];
    qs = s;
  }
  __syncthreads();
  if (t < NC) out_q[(size_t)v * NC + t] = qv[t] / qs;
}

extern "C" void kernel_launch(void* const* d_in, const int* in_sizes, int n_in, void* d_out,
                              int out_size, void* d_ws, size_t ws_size, hipStream_t stream) {
  const float* x = (const float*)d_in[0];
  const int* ei = (const int*)d_in[1];
  const float* W_s1 = (const float*)d_in[2];
  const float* b_s1 = (const float*)d_in[3];
  const float* W_s2 = (const float*)d_in[4];
  const float* b_s2 = (const float*)d_in[5];
  const float* W_t1 = (const float*)d_in[6];
  const float* b_t1 = (const float*)d_in[7];
  const float* W_t2 = (const float*)d_in[8];
  const float* b_t2 = (const float*)d_in[9];
  const float* fw = (const float*)d_in[10];
  const float* cent = (const float*)d_in[11];
  float* out_z = (float*)d_out;
  float* out_q = out_z + (size_t)N_NODES * EMB;

  char* w = (char*)d_ws;
  size_t o = 0;
  auto alloc = [&](size_t bytes) -> void* {
    void* p = w + o;
    o += (bytes + 255) & ~(size_t)255;
    return p;
  };
  // xnf (normalized f16, simgemm input) -> h1_s f32 after simgemm (both 10.24 MB)
  unsigned short* xnf = (unsigned short*)alloc((size_t)N_NODES * FEAT * 2);
  float* h1_s = (float*)xnf;
  // xf (raw f16, layer-1 GEMM input) -> h2_s/h2_t f32 after layer-1 GEMMs (10.24 MB)
  unsigned short* xf = (unsigned short*)alloc((size_t)N_NODES * FEAT * 2);
  float* h2_s = (float*)xf;
  float* h2_t = (float*)xf + (size_t)N_NODES * EMB;
  double* rinv = (double*)alloc((size_t)N_NODES * 8);
  // cap_buf (5.12 MB) -> r1_s f16 after k_knn (both 5.12 MB)
  unsigned int* cap_buf = (unsigned int*)alloc((size_t)N_NODES * CAP * 4);
  unsigned short* r1_s = (unsigned short*)cap_buf;
  unsigned short* r1_t = (unsigned short*)alloc((size_t)N_NODES * HID * 2);
  float* h1_t = (float*)alloc((size_t)N_NODES * HID * 4);
  float* z_s = (float*)alloc((size_t)N_NODES * EMB * 4);
  float* z_t = (float*)alloc((size_t)N_NODES * EMB * 4);
  int* nb = (int*)alloc((size_t)N_NODES * NNB * 4);
  int* cnt_s = (int*)alloc((size_t)N_NODES * 4);
  int* off_s = (int*)alloc((size_t)(N_NODES + 1) * 4);
  int* cur_s = (int*)alloc((size_t)N_NODES * 4);
  float* dinv_s = (float*)alloc((size_t)N_NODES * 4);
  int* cnt_t = (int*)alloc((size_t)N_NODES * 4);
  int* off_t = (int*)alloc((size_t)(N_NODES + 1) * 4);
  int* cur_t = (int*)alloc((size_t)N_NODES * 4);
  float* dinv_t = (float*)alloc((size_t)N_NODES * 4);
  int* csr_s = (int*)alloc((size_t)NE_EDGES * 4);
  int* csr_t = (int*)alloc((size_t)N_NODES * NNB * 4);
  int* cnt_row = (int*)alloc((size_t)N_NODES * 4);
  int* flags = (int*)alloc((size_t)N_NODES * 4);
  unsigned short* Wt_s1 = (unsigned short*)alloc((size_t)FEAT * HID * 2);
  unsigned short* Wt_t1 = (unsigned short*)alloc((size_t)FEAT * HID * 2);
  unsigned short* Wt_s2 = (unsigned short*)alloc((size_t)HID * EMB * 2);
  unsigned short* Wt_t2 = (unsigned short*)alloc((size_t)HID * EMB * 2);

  const int* e_src = ei;
  const int* e_dst = ei + NE_EDGES;

  // 1. norms -> f16 normalized + f16 raw + f64 inv norms; weight transposes
  k_norms<<<N_NODES, 128, 0, stream>>>(x, xnf, xf, rinv);
  k_wt<<<(FEAT * HID + 255) / 256, 256, 0, stream>>>(W_s1, Wt_s1, FEAT, HID);
  k_wt<<<(FEAT * HID + 255) / 256, 256, 0, stream>>>(W_t1, Wt_t1, FEAT, HID);
  k_wt<<<(HID * EMB + 255) / 256, 256, 0, stream>>>(W_s2, Wt_s2, HID, EMB);
  k_wt<<<(HID * EMB + 255) / 256, 256, 0, stream>>>(W_t2, Wt_t2, HID, EMB);
  // 2. zero counters
  k_zero<<<(N_NODES + 255) / 256, 256, 0, stream>>>(cnt_s, N_NODES);
  k_zero<<<(N_NODES + 255) / 256, 256, 0, stream>>>(cnt_t, N_NODES);
  k_zero<<<(N_NODES + 255) / 256, 256, 0, stream>>>(cnt_row, N_NODES);
  k_count<<<(NE_EDGES + 255) / 256, 256, 0, stream>>>(e_dst, NE_EDGES, cnt_s);
  // 3. sim GEMM (upper triangle, XCD-chunked, counted-vmcnt pipeline) + threshold filter
  k_simgemm<<<NPAIR, 256, 0, stream>>>(xnf, cap_buf, cnt_row);
  // 4. fused select + exact f64 rescore -> 9 neighbors; fallback for flagged rows
  k_knn<<<N_NODES, 256, 0, stream>>>(x, rinv, cap_buf, cnt_row, nb, flags);
  k_fallback<<<N_NODES, 256, 0, stream>>>(x, rinv, flags, nb);
  // 5. topology degrees + scans + scatter
  k_count<<<(N_NODES * NNB + 255) / 256, 256, 0, stream>>>(nb, N_NODES * NNB, cnt_t);
  k_scan<<<1, 1024, 0, stream>>>(cnt_s, N_NODES, off_s, cur_s, dinv_s);
  k_scan<<<1, 1024, 0, stream>>>(cnt_t, N_NODES, off_t, cur_t, dinv_t);
  k_scatter_s<<<(NE_EDGES + 255) / 256, 256, 0, stream>>>(e_src, e_dst, NE_EDGES, cur_s, csr_s);
  k_scatter_t<<<(N_NODES * NNB + 255) / 256, 256, 0, stream>>>(nb, cur_t, csr_t);
  // 6. layer-1 f16 MFMA GEMMs, merged pair (h1_s aliases xnf: safe, simgemm done)
  {
    dim3 g1(NTB, 2 * (HID / 128));
    k_fgemm2<<<g1, 256, 0, stream>>>(xf, xf, Wt_s1, Wt_t1, h1_s, h1_t, N_NODES, FEAT, HID);
  }
  // 7. layer-1 aggregation + relu -> f16 r1 (r1_s overwrites cap_buf: safe, k_knn done)
  k_agg_h<<<N_NODES, HID, 0, stream>>>(h1_s, b_s1, dinv_s, off_s, csr_s, r1_s);
  k_agg_h<<<N_NODES, HID, 0, stream>>>(h1_t, b_t1, dinv_t, off_t, csr_t, r1_t);
  // 8. layer-2 f16 MFMA GEMMs, merged pair (h2_s/h2_t alias xf: safe, layer-1 GEMMs done)
  {
    dim3 g2(NTB, 2 * (EMB / 128));
    k_fgemm2<<<g2, 256, 0, stream>>>(r1_s, r1_t, Wt_s2, Wt_t2, h2_s, h2_t, N_NODES, HID, EMB);
  }
  // 9. layer-2 aggregation
  k_agg<<<N_NODES, EMB, 0, stream>>>(h2_s, b_s2, dinv_s, off_s, csr_s, z_s);
  k_agg<<<N_NODES, EMB, 0, stream>>>(h2_t, b_t2, dinv_t, off_t, csr_t, z_t);
  // 10. fusion + soft assignment
  k_fuse<<<N_NODES, 128, 0, stream>>>(z_s, z_t, fw, cent, out_z, out_q);
}